// Round 13
// baseline (734.274 us; speedup 1.0000x reference)
//
#include <hip/hip_runtime.h>
#include <hip/hip_fp16.h>

#define HIDDIM 256
#define NHEADS 8
#define SCORE_SHIFT 4.0f

struct __attribute__((aligned(8)))  half4s { __half2 a, b; };

typedef _Float16 f16x8 __attribute__((ext_vector_type(8)));
typedef float f32x4 __attribute__((ext_vector_type(4)));

// ---------------- converts ----------------
__global__ __launch_bounds__(256) void cvt_f2h(
    const float* __restrict__ in, __half* __restrict__ out, int n) {
  const int i = blockIdx.x * 256 + threadIdx.x;
  if (i < n) out[i] = __float2half(in[i]);
}

// in [K][N] fp32 -> out [N][K] fp16 (transposed)
__global__ __launch_bounds__(256) void cvt_transpose(
    const float* __restrict__ in, __half* __restrict__ out, int K, int N) {
  const int idx = blockIdx.x * 256 + threadIdx.x;
  if (idx >= K * N) return;
  const int n = idx / K, k = idx - n * K;
  out[idx] = __float2half(in[(size_t)k * N + n]);
}

// ---------------- MFMA GEMM: C16[M,N] = act(A16[M,K] @ Wt16[N,K]^T + bias) ----------------
template <int RELU>
__global__ __launch_bounds__(256) void gemm_mfma(
    const _Float16* __restrict__ A, const _Float16* __restrict__ Wt,
    const float* __restrict__ bias, _Float16* __restrict__ C,
    int M, int N, int K) {
  const int wv = threadIdx.x >> 6;
  const int lane = threadIdx.x & 63;
  const int bn = blockIdx.x * 64;
  const int bm = blockIdx.y * 64 + wv * 16;
  const int fr = lane & 15;
  const int kb = lane >> 4;

  int arow = bm + fr; if (arow >= M) arow = M - 1;
  const _Float16* ap = A + (size_t)arow * K + kb * 8;
  const _Float16* bp = Wt + (size_t)(bn + fr) * K + kb * 8;

  f32x4 acc[4] = {};
  for (int k0 = 0; k0 < K; k0 += 32) {
    const f16x8 a = *(const f16x8*)(ap + k0);
    #pragma unroll
    for (int nt = 0; nt < 4; ++nt) {
      const f16x8 b = *(const f16x8*)(bp + (size_t)nt * 16 * K + k0);
      acc[nt] = __builtin_amdgcn_mfma_f32_16x16x32_f16(a, b, acc[nt], 0, 0, 0);
    }
  }
  #pragma unroll
  for (int r = 0; r < 4; ++r) {
    const int row = bm + (lane >> 4) * 4 + r;
    if (row >= M) continue;
    #pragma unroll
    for (int nt = 0; nt < 4; ++nt) {
      const int col = bn + nt * 16 + fr;
      float v = acc[nt][r] + bias[col];
      if (RELU && v < 0.f) v = 0.f;
      C[(size_t)row * N + col] = (_Float16)v;
    }
  }
}

// ---------------- CSR build (by destination; stores SRC node id) ----------------
__global__ __launch_bounds__(256) void count_deg(
    const int* __restrict__ ei, int* __restrict__ deg, int E, int Nn) {
  const int t = blockIdx.x * blockDim.x + threadIdx.x;
  const int ET = E + Nn;
  if (t >= ET) return;
  const int dst = (t < E) ? ei[E + t] : (t - E);
  atomicAdd(&deg[dst], 1);
}

__global__ __launch_bounds__(1024) void scan_deg(
    const int* __restrict__ deg, int* __restrict__ rowptr, int Nn) {
  __shared__ int wsum[16];
  __shared__ int carry_s;
  const int tid = threadIdx.x;
  const int wid = tid >> 6, lane = tid & 63;
  if (tid == 0) { carry_s = 0; rowptr[0] = 0; }
  __syncthreads();
  for (int base = 0; base < Nn; base += 1024) {
    const int i = base + tid;
    int s = (i < Nn) ? deg[i] : 0;
    #pragma unroll
    for (int off = 1; off < 64; off <<= 1) {
      int t = __shfl_up(s, off);
      if (lane >= off) s += t;
    }
    if (lane == 63) wsum[wid] = s;
    __syncthreads();
    if (wid == 0 && lane < 16) {
      int ws = wsum[lane];
      #pragma unroll
      for (int off = 1; off < 16; off <<= 1) {
        int t = __shfl_up(ws, off);
        if (lane >= off) ws += t;
      }
      wsum[lane] = ws;
    }
    __syncthreads();
    const int prefix = (wid > 0 ? wsum[wid - 1] : 0) + carry_s;
    if (i < Nn) rowptr[i + 1] = s + prefix;
    __syncthreads();
    if (tid == 0) carry_s += wsum[15];
    __syncthreads();
  }
}

__global__ __launch_bounds__(256) void fill_csr(
    const int* __restrict__ ei, const int* __restrict__ rowptr,
    int* __restrict__ cursor, int* __restrict__ csr, int E, int Nn) {
  const int t = blockIdx.x * blockDim.x + threadIdx.x;
  const int ET = E + Nn;
  if (t >= ET) return;
  int src, dst;
  if (t < E) { src = ei[t]; dst = ei[E + t]; }
  else { src = t - E; dst = t - E; }
  const int pos = atomicAdd(&cursor[dst], 1);
  csr[rowptr[dst] + pos] = src;
}

// ---------------- node_part: quartered fused GATv2 partial aggregation ----------------
// wave W handles node n=W>>2, quarter q=W&3: slots [r0+(deg*q)/4, r0+(deg*(q+1))/4).
// lane owns channels [4*lane,4*lane+4); head h = lane>>3.
// max-free softmax w = exp(s - SHIFT); writes partial (sum w*xl) fp16 + (sum w) fp32.
__global__ __launch_bounds__(256) void node_part(
    const __half* __restrict__ xl, const __half* __restrict__ xr,
    const int* __restrict__ rowptr, const int* __restrict__ csr,
    const float* __restrict__ att,
    __half* __restrict__ pacc, float* __restrict__ pden, int Nn) {
  const int gw = (int)((blockIdx.x * (size_t)blockDim.x + threadIdx.x) >> 6);
  const int lane = threadIdx.x & 63;
  int n = gw >> 2;
  const int q = gw & 3;
  if (n >= Nn) return;
  n = __builtin_amdgcn_readfirstlane(n);
  const int r0 = rowptr[n], r1 = rowptr[n + 1];
  const int deg = r1 - r0;
  const int s0 = r0 + ((deg * q) >> 2);
  const int s1 = r0 + ((deg * (q + 1)) >> 2);

  const half4s* __restrict__ xlv = (const half4s*)xl;
  float4 acc = make_float4(0.f, 0.f, 0.f, 0.f);
  float den = 0.f;

  if (s0 < s1) {
    float4 xr4;
    {
      const half4s xh = *((const half4s*)xr + (size_t)n * (HIDDIM / 4) + lane);
      const float2 f01 = __half22float2(xh.a);
      const float2 f23 = __half22float2(xh.b);
      xr4 = make_float4(f01.x, f01.y, f23.x, f23.y);
    }
    const float4 at4 = *(const float4*)(att + lane * 4);
    const int jm = s1 - 1;

    for (int j0 = s0; j0 <= jm; j0 += 8) {
      half4s r[8];
      #pragma unroll
      for (int k = 0; k < 8; ++k) {
        int j = j0 + k; j = j <= jm ? j : jm;
        r[k] = xlv[(size_t)csr[j] * (HIDDIM / 4) + lane];
      }
      float4 a[8];
      float s[8];
      #pragma unroll
      for (int k = 0; k < 8; ++k) {
        const float2 f01 = __half22float2(r[k].a);
        const float2 f23 = __half22float2(r[k].b);
        a[k] = make_float4(f01.x, f01.y, f23.x, f23.y);
        float v, ss;
        v = a[k].x + xr4.x; v = v >= 0.f ? v : 0.2f * v; ss = v * at4.x;
        v = a[k].y + xr4.y; v = v >= 0.f ? v : 0.2f * v; ss = fmaf(v, at4.y, ss);
        v = a[k].z + xr4.z; v = v >= 0.f ? v : 0.2f * v; ss = fmaf(v, at4.z, ss);
        v = a[k].w + xr4.w; v = v >= 0.f ? v : 0.2f * v; ss = fmaf(v, at4.w, ss);
        s[k] = ss;
      }
      #pragma unroll
      for (int k = 0; k < 8; ++k) {
        s[k] += __shfl_xor(s[k], 1);
        s[k] += __shfl_xor(s[k], 2);
        s[k] += __shfl_xor(s[k], 4);
      }
      float w[8];
      #pragma unroll
      for (int k = 0; k < 8; ++k)
        w[k] = (j0 + k <= jm) ? __expf(s[k] - SCORE_SHIFT) : 0.f;
      #pragma unroll
      for (int k = 0; k < 8; ++k) {
        acc.x = fmaf(w[k], a[k].x, acc.x);
        acc.y = fmaf(w[k], a[k].y, acc.y);
        acc.z = fmaf(w[k], a[k].z, acc.z);
        acc.w = fmaf(w[k], a[k].w, acc.w);
        den += w[k];
      }
    }
  }

  // write partial: pacc[n][q][256] fp16, pden[n][q][8] fp32
  half4s po;
  po.a = __floats2half2_rn(acc.x, acc.y);
  po.b = __floats2half2_rn(acc.z, acc.w);
  *((half4s*)pacc + ((size_t)n * 4 + q) * (HIDDIM / 4) + lane) = po;
  if ((lane & 7) == 0)
    pden[((size_t)n * 4 + q) * NHEADS + (lane >> 3)] = den;
}

// ---------------- node_fin: merge 4 partials + epilogue ----------------
// MODE 0: layernorm(relu(agg+bias)) -> fp16 outp ; MODE 1: pool
template <int MODE>
__global__ __launch_bounds__(256) void node_fin(
    const __half* __restrict__ pacc, const float* __restrict__ pden,
    const float* __restrict__ bias, const float* __restrict__ lng,
    const float* __restrict__ lnb, const int* __restrict__ batch,
    float* __restrict__ pooled, float* __restrict__ counts,
    __half* __restrict__ outp, int Nn) {
  const int n = (int)((blockIdx.x * (size_t)blockDim.x + threadIdx.x) >> 6);
  const int lane = threadIdx.x & 63;
  if (n >= Nn) return;
  const int h = lane >> 3;

  float4 acc = make_float4(0.f, 0.f, 0.f, 0.f);
  float den = 0.f;
  #pragma unroll
  for (int q = 0; q < 4; ++q) {
    const half4s p = *((const half4s*)pacc + ((size_t)n * 4 + q) * (HIDDIM / 4) + lane);
    const float2 f01 = __half22float2(p.a);
    const float2 f23 = __half22float2(p.b);
    acc.x += f01.x; acc.y += f01.y; acc.z += f23.x; acc.w += f23.y;
    den += pden[((size_t)n * 4 + q) * NHEADS + h];
  }
  const float inv_d = 1.f / den;

  const float4 bb = *(const float4*)(bias + lane * 4);
  float t0 = fmaf(acc.x, inv_d, bb.x); t0 = t0 > 0.f ? t0 : 0.f;
  float t1 = fmaf(acc.y, inv_d, bb.y); t1 = t1 > 0.f ? t1 : 0.f;
  float t2 = fmaf(acc.z, inv_d, bb.z); t2 = t2 > 0.f ? t2 : 0.f;
  float t3 = fmaf(acc.w, inv_d, bb.w); t3 = t3 > 0.f ? t3 : 0.f;

  if (MODE == 0) {
    float s = t0 + t1 + t2 + t3;
    #pragma unroll
    for (int mm = 1; mm < 64; mm <<= 1) s += __shfl_xor(s, mm);
    const float mu = s * (1.f / HIDDIM);
    const float d0 = t0 - mu, d1 = t1 - mu, d2 = t2 - mu, d3 = t3 - mu;
    float qq = d0 * d0 + d1 * d1 + d2 * d2 + d3 * d3;
    #pragma unroll
    for (int mm = 1; mm < 64; mm <<= 1) qq += __shfl_xor(qq, mm);
    const float inv = rsqrtf(qq * (1.f / HIDDIM) + 1e-5f);
    const float4 g4 = *(const float4*)(lng + lane * 4);
    const float4 b4 = *(const float4*)(lnb + lane * 4);
    half4s ho;
    ho.a = __floats2half2_rn(d0 * inv * g4.x + b4.x, d1 * inv * g4.y + b4.y);
    ho.b = __floats2half2_rn(d2 * inv * g4.z + b4.z, d3 * inv * g4.w + b4.w);
    *((half4s*)outp + (size_t)n * (HIDDIM / 4) + lane) = ho;
  } else {
    const int g = batch[n];
    float* p = pooled + (size_t)g * HIDDIM + lane * 4;
    atomicAdd(p + 0, t0);
    atomicAdd(p + 1, t1);
    atomicAdd(p + 2, t2);
    atomicAdd(p + 3, t3);
    if (lane == 0) atomicAdd(&counts[g], 1.f);
  }
}

// ---------------- head MLP ----------------
__global__ __launch_bounds__(256) void head_kernel(
    const float* __restrict__ pooled, const float* __restrict__ counts,
    const float* __restrict__ h1w, const float* __restrict__ h1b,
    const float* __restrict__ h2w, const float* __restrict__ h2b,
    float* __restrict__ out, int G, int H1, int OUT) {
  __shared__ float P[16][HIDDIM];
  __shared__ float Hh[16][128];
  const int tid = threadIdx.x;
  for (int i = tid; i < G * HIDDIM; i += 256) {
    const int g = i / HIDDIM, c = i % HIDDIM;
    float cnt = counts[g];
    if (cnt < 1.f) cnt = 1.f;
    P[g][c] = pooled[i] / cnt;
  }
  __syncthreads();
  for (int i = tid; i < G * H1; i += 256) {
    const int g = i / H1, j = i % H1;
    float s = h1b[j];
    for (int k = 0; k < HIDDIM; ++k) s = fmaf(P[g][k], h1w[k * H1 + j], s);
    Hh[g][j] = s > 0.f ? s : 0.f;
  }
  __syncthreads();
  for (int i = tid; i < G * OUT; i += 256) {
    const int g = i / OUT, o = i % OUT;
    float s = h2b[o];
    for (int k = 0; k < H1; ++k) s = fmaf(Hh[g][k], h2w[k * OUT + o], s);
    out[i] = s;
  }
}

extern "C" void kernel_launch(void* const* d_in, const int* in_sizes, int n_in,
                              void* d_out, int out_size, void* d_ws, size_t ws_size,
                              hipStream_t stream) {
  const float* x = (const float*)d_in[0];
  const int* ei = (const int*)d_in[1];
  const int* batch = (const int*)d_in[2];
  const float* enc_w = (const float*)d_in[3];
  const float* enc_b = (const float*)d_in[4];
  const float* g_wl[2] = {(const float*)d_in[5], (const float*)d_in[11]};
  const float* g_bl[2] = {(const float*)d_in[6], (const float*)d_in[12]};
  const float* g_wr[2] = {(const float*)d_in[7], (const float*)d_in[13]};
  const float* g_br[2] = {(const float*)d_in[8], (const float*)d_in[14]};
  const float* g_att[2] = {(const float*)d_in[9], (const float*)d_in[15]};
  const float* g_bias[2] = {(const float*)d_in[10], (const float*)d_in[16]};
  const float* ln_g = (const float*)d_in[17];
  const float* ln_b = (const float*)d_in[18];
  const float* h1_w = (const float*)d_in[19];
  const float* h1_b = (const float*)d_in[20];
  const float* h2_w = (const float*)d_in[21];
  const float* h2_b = (const float*)d_in[22];
  float* out = (float*)d_out;

  const int N = in_sizes[2];          // 20000
  const int E = in_sizes[1] / 2;      // 320000
  const int DIN = in_sizes[0] / N;    // 128
  const int ET = E + N;
  const int H1 = in_sizes[20];        // 128
  const int OUT = in_sizes[22];       // 2
  const int G = out_size / OUT;       // 16

  char* base = (char*)d_ws;
  const size_t NH = (size_t)N * HIDDIM;
  __half* h16  = (__half*)base;                    // [N][256]
  __half* xl16 = h16 + NH;
  __half* xr16 = xl16 + NH;
  __half* x16  = xr16 + NH;                        // [N][DIN]
  __half* wtE  = x16 + (size_t)N * DIN;            // [256][DIN]
  __half* wt[4];
  wt[0] = wtE + (size_t)HIDDIM * DIN;
  wt[1] = wt[0] + (size_t)HIDDIM * HIDDIM;
  wt[2] = wt[1] + (size_t)HIDDIM * HIDDIM;
  wt[3] = wt[2] + (size_t)HIDDIM * HIDDIM;
  __half* pacc = wt[3] + (size_t)HIDDIM * HIDDIM;  // [N][4][256] fp16
  float* pden  = (float*)(pacc + NH * 4);          // [N][4][8] fp32
  float* pooled = pden + (size_t)N * 4 * NHEADS;
  float* counts = pooled + (size_t)G * HIDDIM;
  int* deg    = (int*)(counts + G);
  int* rowptr = deg + N;
  int* cursor = rowptr + (N + 1);
  int* csr    = cursor + N;

  const dim3 blk(256);
  const int eb = (ET + 255) / 256;
  const int nb = (N + 3) / 4;
  const dim3 mfma_grid(HIDDIM / 64, (N + 63) / 64);

  // CSR build (graph identical for both layers)
  hipMemsetAsync(deg, 0, (size_t)N * sizeof(int), stream);
  hipMemsetAsync(cursor, 0, (size_t)N * sizeof(int), stream);
  hipMemsetAsync(pooled, 0, ((size_t)G * HIDDIM + G) * sizeof(float), stream);
  count_deg<<<eb, blk, 0, stream>>>(ei, deg, E, N);
  scan_deg<<<1, 1024, 0, stream>>>(deg, rowptr, N);
  fill_csr<<<eb, blk, 0, stream>>>(ei, rowptr, cursor, csr, E, N);

  // weight/input conversion
  cvt_f2h<<<(N * DIN + 255) / 256, blk, 0, stream>>>(x, x16, N * DIN);
  cvt_transpose<<<(DIN * HIDDIM + 255) / 256, blk, 0, stream>>>(enc_w, wtE, DIN, HIDDIM);
  cvt_transpose<<<(HIDDIM * HIDDIM + 255) / 256, blk, 0, stream>>>(g_wl[0], wt[0], HIDDIM, HIDDIM);
  cvt_transpose<<<(HIDDIM * HIDDIM + 255) / 256, blk, 0, stream>>>(g_wr[0], wt[1], HIDDIM, HIDDIM);
  cvt_transpose<<<(HIDDIM * HIDDIM + 255) / 256, blk, 0, stream>>>(g_wl[1], wt[2], HIDDIM, HIDDIM);
  cvt_transpose<<<(HIDDIM * HIDDIM + 255) / 256, blk, 0, stream>>>(g_wr[1], wt[3], HIDDIM, HIDDIM);

  // encoder: h16 = relu(x @ enc_w + enc_b)
  gemm_mfma<1><<<mfma_grid, blk, 0, stream>>>(
      (const _Float16*)x16, (const _Float16*)wtE, enc_b, (_Float16*)h16, N, HIDDIM, DIN);

  for (int L = 0; L < 2; ++L) {
    gemm_mfma<0><<<mfma_grid, blk, 0, stream>>>(
        (const _Float16*)h16, (const _Float16*)wt[2 * L + 0], g_bl[L], (_Float16*)xl16, N, HIDDIM, HIDDIM);
    gemm_mfma<0><<<mfma_grid, blk, 0, stream>>>(
        (const _Float16*)h16, (const _Float16*)wt[2 * L + 1], g_br[L], (_Float16*)xr16, N, HIDDIM, HIDDIM);
    // quartered partial aggregation: 4N waves = N blocks of 4 waves
    node_part<<<N, blk, 0, stream>>>(xl16, xr16, rowptr, csr, g_att[L], pacc, pden, N);
    if (L == 0) {
      node_fin<0><<<nb, blk, 0, stream>>>(pacc, pden, g_bias[0], ln_g, ln_b,
                                          nullptr, nullptr, nullptr, h16, N);
    } else {
      node_fin<1><<<nb, blk, 0, stream>>>(pacc, pden, g_bias[1], nullptr, nullptr,
                                          batch, pooled, counts, nullptr, N);
    }
  }
  head_kernel<<<1, blk, 0, stream>>>(pooled, counts, h1_w, h1_b, h2_w, h2_b, out, G, H1, OUT);
}

// Round 14
// 385.251 us; speedup vs baseline: 1.9060x; 1.9060x over previous
//
#include <hip/hip_runtime.h>
#include <hip/hip_fp16.h>

#define HIDDIM 256
#define NHEADS 8
#define SCORE_SHIFT 4.0f
#define XSTR 512   // xlr row stride (xl cols 0-255, xr cols 256-511)

struct __attribute__((aligned(8))) half4s { __half2 a, b; };

typedef _Float16 f16x8 __attribute__((ext_vector_type(8)));
typedef float f32x4 __attribute__((ext_vector_type(4)));

// ---------------- converts ----------------
__global__ __launch_bounds__(256) void cvt_f2h(
    const float* __restrict__ in, __half* __restrict__ out, int n) {
  const int i = blockIdx.x * 256 + threadIdx.x;
  if (i < n) out[i] = __float2half(in[i]);
}

// in [K][N] fp32 -> out [N][K] fp16 (transposed)
__global__ __launch_bounds__(256) void cvt_transpose(
    const float* __restrict__ in, __half* __restrict__ out, int K, int N) {
  const int idx = blockIdx.x * 256 + threadIdx.x;
  if (idx >= K * N) return;
  const int n = idx / K, k = idx - n * K;
  out[idx] = __float2half(in[(size_t)k * N + n]);
}

// concat two [n] fp32 vectors -> [2n]
__global__ __launch_bounds__(256) void concat2(
    const float* __restrict__ a, const float* __restrict__ b,
    float* __restrict__ o, int n) {
  const int i = blockIdx.x * 256 + threadIdx.x;
  if (i < n) o[i] = a[i];
  else if (i < 2 * n) o[i] = b[i - n];
}

// ---------------- MFMA GEMM: C16[M,N] = act(A16[M,K] @ Wt16[N,K]^T + bias) ----------------
template <int RELU>
__global__ __launch_bounds__(256) void gemm_mfma(
    const _Float16* __restrict__ A, const _Float16* __restrict__ Wt,
    const float* __restrict__ bias, _Float16* __restrict__ C,
    int M, int N, int K) {
  const int wv = threadIdx.x >> 6;
  const int lane = threadIdx.x & 63;
  const int bn = blockIdx.x * 64;
  const int bm = blockIdx.y * 64 + wv * 16;
  const int fr = lane & 15;
  const int kb = lane >> 4;

  int arow = bm + fr; if (arow >= M) arow = M - 1;
  const _Float16* ap = A + (size_t)arow * K + kb * 8;
  const _Float16* bp = Wt + (size_t)(bn + fr) * K + kb * 8;

  f32x4 acc[4] = {};
  for (int k0 = 0; k0 < K; k0 += 32) {
    const f16x8 a = *(const f16x8*)(ap + k0);
    #pragma unroll
    for (int nt = 0; nt < 4; ++nt) {
      const f16x8 b = *(const f16x8*)(bp + (size_t)nt * 16 * K + k0);
      acc[nt] = __builtin_amdgcn_mfma_f32_16x16x32_f16(a, b, acc[nt], 0, 0, 0);
    }
  }
  #pragma unroll
  for (int r = 0; r < 4; ++r) {
    const int row = bm + (lane >> 4) * 4 + r;
    if (row >= M) continue;
    #pragma unroll
    for (int nt = 0; nt < 4; ++nt) {
      const int col = bn + nt * 16 + fr;
      float v = acc[nt][r] + bias[col];
      if (RELU && v < 0.f) v = 0.f;
      C[(size_t)row * N + col] = (_Float16)v;
    }
  }
}

// ---------------- CSR build (by destination; stores SRC node id) ----------------
__global__ __launch_bounds__(256) void count_deg(
    const int* __restrict__ ei, int* __restrict__ deg, int E, int Nn) {
  const int t = blockIdx.x * blockDim.x + threadIdx.x;
  const int ET = E + Nn;
  if (t >= ET) return;
  const int dst = (t < E) ? ei[E + t] : (t - E);
  atomicAdd(&deg[dst], 1);
}

__global__ __launch_bounds__(1024) void scan_deg(
    const int* __restrict__ deg, int* __restrict__ rowptr, int Nn) {
  __shared__ int wsum[16];
  __shared__ int carry_s;
  const int tid = threadIdx.x;
  const int wid = tid >> 6, lane = tid & 63;
  if (tid == 0) { carry_s = 0; rowptr[0] = 0; }
  __syncthreads();
  for (int base = 0; base < Nn; base += 1024) {
    const int i = base + tid;
    int s = (i < Nn) ? deg[i] : 0;
    #pragma unroll
    for (int off = 1; off < 64; off <<= 1) {
      int t = __shfl_up(s, off);
      if (lane >= off) s += t;
    }
    if (lane == 63) wsum[wid] = s;
    __syncthreads();
    if (wid == 0 && lane < 16) {
      int ws = wsum[lane];
      #pragma unroll
      for (int off = 1; off < 16; off <<= 1) {
        int t = __shfl_up(ws, off);
        if (lane >= off) ws += t;
      }
      wsum[lane] = ws;
    }
    __syncthreads();
    const int prefix = (wid > 0 ? wsum[wid - 1] : 0) + carry_s;
    if (i < Nn) rowptr[i + 1] = s + prefix;
    __syncthreads();
    if (tid == 0) carry_s += wsum[15];
    __syncthreads();
  }
}

__global__ __launch_bounds__(256) void fill_csr(
    const int* __restrict__ ei, const int* __restrict__ rowptr,
    int* __restrict__ cursor, int* __restrict__ csr, int E, int Nn) {
  const int t = blockIdx.x * blockDim.x + threadIdx.x;
  const int ET = E + Nn;
  if (t >= ET) return;
  int src, dst;
  if (t < E) { src = ei[t]; dst = ei[E + t]; }
  else { src = t - E; dst = t - E; }
  const int pos = atomicAdd(&cursor[dst], 1);
  csr[rowptr[dst] + pos] = src;
}

// ---------------- graph ranges from sorted batch ----------------
__global__ __launch_bounds__(256) void graph_ranges(
    const int* __restrict__ batch, int* __restrict__ gstart, int Nn, int G) {
  const int n = blockIdx.x * 256 + threadIdx.x;
  if (n > Nn) return;
  if (n == 0) {
    for (int g = 0; g <= batch[0]; ++g) gstart[g] = 0;
  } else if (n == Nn) {
    for (int g = batch[Nn - 1] + 1; g <= G; ++g) gstart[g] = Nn;
  } else {
    const int b = batch[n], bp = batch[n - 1];
    for (int g = bp + 1; g <= b; ++g) gstart[g] = n;
  }
}

// ---------------- fused single-pass GATv2 per-node (xlr stride 512) ----------------
// one wave per node; lane covers channels [4*lane,4*lane+4); head h = lane>>3
// MODE 0: layernorm(relu(agg+bias)) -> fp16 outp ; MODE 1: relu(agg+bias) -> tbuf (no atomics)
template <int MODE>
__global__ __launch_bounds__(256) void node_gat(
    const __half* __restrict__ xlr,
    const int* __restrict__ rowptr, const int* __restrict__ csr,
    const float* __restrict__ att, const float* __restrict__ bias,
    const float* __restrict__ lng, const float* __restrict__ lnb,
    __half* __restrict__ outp, int Nn) {
  int n = (int)((blockIdx.x * (size_t)blockDim.x + threadIdx.x) >> 6);
  const int lane = threadIdx.x & 63;
  if (n >= Nn) return;
  n = __builtin_amdgcn_readfirstlane(n);
  const int r0 = rowptr[n], r1 = rowptr[n + 1];
  const int jm = r1 - 1;
  const half4s* __restrict__ xlv = (const half4s*)xlr;       // row stride XSTR/4 = 128
  float4 xr4;
  {
    const half4s xrh = xlv[(size_t)n * (XSTR / 4) + 64 + lane];   // xr = cols 256-511
    const float2 f01 = __half22float2(xrh.a);
    const float2 f23 = __half22float2(xrh.b);
    xr4 = make_float4(f01.x, f01.y, f23.x, f23.y);
  }
  const float4 at4 = *(const float4*)(att + lane * 4);
  float4 acc = make_float4(0.f, 0.f, 0.f, 0.f);
  float den = 0.f;

  for (int j0 = r0; j0 <= jm; j0 += 8) {
    half4s r[8];
    #pragma unroll
    for (int k = 0; k < 8; ++k) {
      int j = j0 + k; j = j <= jm ? j : jm;
      r[k] = xlv[(size_t)csr[j] * (XSTR / 4) + lane];
    }
    float4 a[8];
    float s[8];
    #pragma unroll
    for (int k = 0; k < 8; ++k) {
      const float2 f01 = __half22float2(r[k].a);
      const float2 f23 = __half22float2(r[k].b);
      a[k] = make_float4(f01.x, f01.y, f23.x, f23.y);
      float v, ss;
      v = a[k].x + xr4.x; v = v >= 0.f ? v : 0.2f * v; ss = v * at4.x;
      v = a[k].y + xr4.y; v = v >= 0.f ? v : 0.2f * v; ss = fmaf(v, at4.y, ss);
      v = a[k].z + xr4.z; v = v >= 0.f ? v : 0.2f * v; ss = fmaf(v, at4.z, ss);
      v = a[k].w + xr4.w; v = v >= 0.f ? v : 0.2f * v; ss = fmaf(v, at4.w, ss);
      s[k] = ss;
    }
    #pragma unroll
    for (int k = 0; k < 8; ++k) {
      s[k] += __shfl_xor(s[k], 1);
      s[k] += __shfl_xor(s[k], 2);
      s[k] += __shfl_xor(s[k], 4);
    }
    float w[8];
    #pragma unroll
    for (int k = 0; k < 8; ++k)
      w[k] = (j0 + k <= jm) ? __expf(s[k] - SCORE_SHIFT) : 0.f;
    #pragma unroll
    for (int k = 0; k < 8; ++k) {
      acc.x = fmaf(w[k], a[k].x, acc.x);
      acc.y = fmaf(w[k], a[k].y, acc.y);
      acc.z = fmaf(w[k], a[k].z, acc.z);
      acc.w = fmaf(w[k], a[k].w, acc.w);
      den += w[k];
    }
  }
  const float inv_d = 1.f / den;
  const float4 bb = *(const float4*)(bias + lane * 4);
  float t0 = fmaf(acc.x, inv_d, bb.x); t0 = t0 > 0.f ? t0 : 0.f;
  float t1 = fmaf(acc.y, inv_d, bb.y); t1 = t1 > 0.f ? t1 : 0.f;
  float t2 = fmaf(acc.z, inv_d, bb.z); t2 = t2 > 0.f ? t2 : 0.f;
  float t3 = fmaf(acc.w, inv_d, bb.w); t3 = t3 > 0.f ? t3 : 0.f;

  if (MODE == 0) {
    float s = t0 + t1 + t2 + t3;
    #pragma unroll
    for (int mm = 1; mm < 64; mm <<= 1) s += __shfl_xor(s, mm);
    const float mu = s * (1.f / HIDDIM);
    const float d0 = t0 - mu, d1 = t1 - mu, d2 = t2 - mu, d3 = t3 - mu;
    float q = d0 * d0 + d1 * d1 + d2 * d2 + d3 * d3;
    #pragma unroll
    for (int mm = 1; mm < 64; mm <<= 1) q += __shfl_xor(q, mm);
    const float inv = rsqrtf(q * (1.f / HIDDIM) + 1e-5f);
    const float4 g4 = *(const float4*)(lng + lane * 4);
    const float4 b4 = *(const float4*)(lnb + lane * 4);
    half4s ho;
    ho.a = __floats2half2_rn(d0 * inv * g4.x + b4.x, d1 * inv * g4.y + b4.y);
    ho.b = __floats2half2_rn(d2 * inv * g4.z + b4.z, d3 * inv * g4.w + b4.w);
    *((half4s*)outp + (size_t)n * (HIDDIM / 4) + lane) = ho;
  } else {
    // no atomics: write relu row to tbuf, pooled reduction happens in pool_kernel
    half4s ho;
    ho.a = __floats2half2_rn(t0, t1);
    ho.b = __floats2half2_rn(t2, t3);
    *((half4s*)outp + (size_t)n * (HIDDIM / 4) + lane) = ho;
  }
}

// ---------------- pool: per-graph contiguous streaming reduction ----------------
// grid (G, 8): block sums rows gstart[g]+rc, step 8, for all 256 channels.
__global__ __launch_bounds__(256) void pool_kernel(
    const __half* __restrict__ tbuf, const int* __restrict__ gstart,
    float* __restrict__ pooled) {
  const int g = blockIdx.x, rc = blockIdx.y, ch = threadIdx.x;
  const int n0 = gstart[g], n1 = gstart[g + 1];
  float acc = 0.f;
  for (int n = n0 + rc; n < n1; n += 8)
    acc += __half2float(tbuf[(size_t)n * HIDDIM + ch]);
  atomicAdd(&pooled[g * HIDDIM + ch], acc);
}

// ---------------- head MLP (counts from gstart) ----------------
__global__ __launch_bounds__(256) void head_kernel(
    const float* __restrict__ pooled, const int* __restrict__ gstart,
    const float* __restrict__ h1w, const float* __restrict__ h1b,
    const float* __restrict__ h2w, const float* __restrict__ h2b,
    float* __restrict__ out, int G, int H1, int OUT) {
  __shared__ float P[16][HIDDIM];
  __shared__ float Hh[16][128];
  const int tid = threadIdx.x;
  for (int i = tid; i < G * HIDDIM; i += 256) {
    const int g = i / HIDDIM, c = i % HIDDIM;
    float cnt = (float)(gstart[g + 1] - gstart[g]);
    if (cnt < 1.f) cnt = 1.f;
    P[g][c] = pooled[i] / cnt;
  }
  __syncthreads();
  for (int i = tid; i < G * H1; i += 256) {
    const int g = i / H1, j = i % H1;
    float s = h1b[j];
    for (int k = 0; k < HIDDIM; ++k) s = fmaf(P[g][k], h1w[k * H1 + j], s);
    Hh[g][j] = s > 0.f ? s : 0.f;
  }
  __syncthreads();
  for (int i = tid; i < G * OUT; i += 256) {
    const int g = i / OUT, o = i % OUT;
    float s = h2b[o];
    for (int k = 0; k < H1; ++k) s = fmaf(Hh[g][k], h2w[k * OUT + o], s);
    out[i] = s;
  }
}

extern "C" void kernel_launch(void* const* d_in, const int* in_sizes, int n_in,
                              void* d_out, int out_size, void* d_ws, size_t ws_size,
                              hipStream_t stream) {
  const float* x = (const float*)d_in[0];
  const int* ei = (const int*)d_in[1];
  const int* batch = (const int*)d_in[2];
  const float* enc_w = (const float*)d_in[3];
  const float* enc_b = (const float*)d_in[4];
  const float* g_wl[2] = {(const float*)d_in[5], (const float*)d_in[11]};
  const float* g_bl[2] = {(const float*)d_in[6], (const float*)d_in[12]};
  const float* g_wr[2] = {(const float*)d_in[7], (const float*)d_in[13]};
  const float* g_br[2] = {(const float*)d_in[8], (const float*)d_in[14]};
  const float* g_att[2] = {(const float*)d_in[9], (const float*)d_in[15]};
  const float* g_bias[2] = {(const float*)d_in[10], (const float*)d_in[16]};
  const float* ln_g = (const float*)d_in[17];
  const float* ln_b = (const float*)d_in[18];
  const float* h1_w = (const float*)d_in[19];
  const float* h1_b = (const float*)d_in[20];
  const float* h2_w = (const float*)d_in[21];
  const float* h2_b = (const float*)d_in[22];
  float* out = (float*)d_out;

  const int N = in_sizes[2];          // 20000
  const int E = in_sizes[1] / 2;      // 320000
  const int DIN = in_sizes[0] / N;    // 128
  const int ET = E + N;
  const int H1 = in_sizes[20];        // 128
  const int OUT = in_sizes[22];       // 2
  const int G = out_size / OUT;       // 16

  char* base = (char*)d_ws;
  const size_t NH = (size_t)N * HIDDIM;
  __half* h16  = (__half*)base;                    // [N][256]
  __half* xlr  = h16 + NH;                         // [N][512]  (xl | xr)
  __half* tbuf = xlr + NH * 2;                     // [N][256]
  __half* x16  = tbuf + NH;                        // [N][DIN]
  __half* wtE  = x16 + (size_t)N * DIN;            // [256][DIN]
  __half* wtC0 = wtE + (size_t)HIDDIM * DIN;       // [512][256]
  __half* wtC1 = wtC0 + (size_t)XSTR * HIDDIM;     // [512][256]
  float* biasC0 = (float*)(wtC1 + (size_t)XSTR * HIDDIM);
  float* biasC1 = biasC0 + XSTR;
  float* pooled = biasC1 + XSTR;                   // [G][256]
  int* gstart = (int*)(pooled + (size_t)G * HIDDIM);  // [G+1]
  int* deg    = gstart + (G + 1);
  int* rowptr = deg + N;
  int* cursor = rowptr + (N + 1);
  int* csr    = cursor + N;

  const dim3 blk(256);
  const int eb = (ET + 255) / 256;
  const int nb = (N + 3) / 4;
  const dim3 enc_grid(HIDDIM / 64, (N + 63) / 64);
  const dim3 cmb_grid(XSTR / 64, (N + 63) / 64);

  // CSR build + graph ranges (graph identical for both layers)
  hipMemsetAsync(deg, 0, (size_t)N * sizeof(int), stream);
  hipMemsetAsync(cursor, 0, (size_t)N * sizeof(int), stream);
  hipMemsetAsync(pooled, 0, (size_t)G * HIDDIM * sizeof(float), stream);
  count_deg<<<eb, blk, 0, stream>>>(ei, deg, E, N);
  scan_deg<<<1, 1024, 0, stream>>>(deg, rowptr, N);
  fill_csr<<<eb, blk, 0, stream>>>(ei, rowptr, cursor, csr, E, N);
  graph_ranges<<<(N + 256) / 256, blk, 0, stream>>>(batch, gstart, N, G);

  // weight/input conversion: combined [Wl|Wr]^T per layer
  cvt_f2h<<<(N * DIN + 255) / 256, blk, 0, stream>>>(x, x16, N * DIN);
  cvt_transpose<<<(DIN * HIDDIM + 255) / 256, blk, 0, stream>>>(enc_w, wtE, DIN, HIDDIM);
  cvt_transpose<<<(HIDDIM * HIDDIM + 255) / 256, blk, 0, stream>>>(g_wl[0], wtC0, HIDDIM, HIDDIM);
  cvt_transpose<<<(HIDDIM * HIDDIM + 255) / 256, blk, 0, stream>>>(g_wr[0], wtC0 + (size_t)HIDDIM * HIDDIM, HIDDIM, HIDDIM);
  cvt_transpose<<<(HIDDIM * HIDDIM + 255) / 256, blk, 0, stream>>>(g_wl[1], wtC1, HIDDIM, HIDDIM);
  cvt_transpose<<<(HIDDIM * HIDDIM + 255) / 256, blk, 0, stream>>>(g_wr[1], wtC1 + (size_t)HIDDIM * HIDDIM, HIDDIM, HIDDIM);
  concat2<<<2, blk, 0, stream>>>(g_bl[0], g_br[0], biasC0, HIDDIM);
  concat2<<<2, blk, 0, stream>>>(g_bl[1], g_br[1], biasC1, HIDDIM);

  // encoder: h16 = relu(x @ enc_w + enc_b)
  gemm_mfma<1><<<enc_grid, blk, 0, stream>>>(
      (const _Float16*)x16, (const _Float16*)wtE, enc_b, (_Float16*)h16, N, HIDDIM, DIN);

  for (int L = 0; L < 2; ++L) {
    const __half* wtC = (L == 0) ? wtC0 : wtC1;
    const float* bC = (L == 0) ? biasC0 : biasC1;
    // one combined GEMM: xlr = h16 @ [Wl|Wr] + [bl|br]
    gemm_mfma<0><<<cmb_grid, blk, 0, stream>>>(
        (const _Float16*)h16, (const _Float16*)wtC, bC, (_Float16*)xlr, N, XSTR, HIDDIM);
    if (L == 0) {
      node_gat<0><<<nb, blk, 0, stream>>>(xlr, rowptr, csr, g_att[0], g_bias[0],
                                          ln_g, ln_b, h16, N);
    } else {
      node_gat<1><<<nb, blk, 0, stream>>>(xlr, rowptr, csr, g_att[1], g_bias[1],
                                          nullptr, nullptr, tbuf, N);
      pool_kernel<<<dim3(G, 8), blk, 0, stream>>>(tbuf, gstart, pooled);
    }
  }
  head_kernel<<<1, blk, 0, stream>>>(pooled, gstart, h1_w, h1_b, h2_w, h2_b, out, G, H1, OUT);
}

// Round 15
// 317.727 us; speedup vs baseline: 2.3110x; 1.2125x over previous
//
#include <hip/hip_runtime.h>
#include <hip/hip_fp16.h>

#define HIDDIM 256
#define NHEADS 8
#define SCORE_SHIFT 4.0f
#define XSTR 512   // xlr row stride (xl cols 0-255, xr cols 256-511)

struct __attribute__((aligned(8))) half4s { __half2 a, b; };

typedef _Float16 f16x8 __attribute__((ext_vector_type(8)));
typedef float f32x4 __attribute__((ext_vector_type(4)));

// ---------------- converts ----------------
__global__ __launch_bounds__(256) void cvt_f2h(
    const float* __restrict__ in, __half* __restrict__ out, int n) {
  const int i = blockIdx.x * 256 + threadIdx.x;
  if (i < n) out[i] = __float2half(in[i]);
}

// in [K][N] fp32 -> out [N][K] fp16 (transposed)
__global__ __launch_bounds__(256) void cvt_transpose(
    const float* __restrict__ in, __half* __restrict__ out, int K, int N) {
  const int idx = blockIdx.x * 256 + threadIdx.x;
  if (idx >= K * N) return;
  const int n = idx / K, k = idx - n * K;
  out[idx] = __float2half(in[(size_t)k * N + n]);
}

// 4 HIDxHID transposes in one launch (blockIdx.y selects)
__global__ __launch_bounds__(256) void cvt_transpose4(
    const float* __restrict__ w0, const float* __restrict__ w1,
    const float* __restrict__ w2, const float* __restrict__ w3,
    __half* __restrict__ o0, __half* __restrict__ o1,
    __half* __restrict__ o2, __half* __restrict__ o3) {
  const float* in; __half* out;
  switch (blockIdx.y) {
    case 0: in = w0; out = o0; break;
    case 1: in = w1; out = o1; break;
    case 2: in = w2; out = o2; break;
    default: in = w3; out = o3; break;
  }
  const int idx = blockIdx.x * 256 + threadIdx.x;
  if (idx >= HIDDIM * HIDDIM) return;
  const int n = idx / HIDDIM, k = idx - n * HIDDIM;
  out[idx] = __float2half(in[(size_t)k * HIDDIM + n]);
}

// both layers' [bl|br] concats in one launch: 2 x 512 floats
__global__ __launch_bounds__(256) void concat_biases(
    const float* __restrict__ bl0, const float* __restrict__ br0,
    const float* __restrict__ bl1, const float* __restrict__ br1,
    float* __restrict__ o0, float* __restrict__ o1) {
  const int i = blockIdx.x * 256 + threadIdx.x;
  if (i >= 2 * XSTR) return;
  const int layer = i >> 9, pos = i & (XSTR - 1);
  const float* bl = layer ? bl1 : bl0;
  const float* br = layer ? br1 : br0;
  float v = (pos < HIDDIM) ? bl[pos] : br[pos - HIDDIM];
  (layer ? o1 : o0)[pos] = v;
}

// ---------------- MFMA GEMM: C16[M,N] = act(A16[M,K] @ Wt16[N,K]^T + bias) ----------------
// block = 64 rows x 128 cols (4 waves x 16 rows); wave does 8 MFMA per 32-k step.
template <int RELU>
__global__ __launch_bounds__(256) void gemm_mfma(
    const _Float16* __restrict__ A, const _Float16* __restrict__ Wt,
    const float* __restrict__ bias, _Float16* __restrict__ C,
    int M, int N, int K) {
  const int wv = threadIdx.x >> 6;
  const int lane = threadIdx.x & 63;
  const int bn = blockIdx.x * 128;
  const int bm = blockIdx.y * 64 + wv * 16;
  const int fr = lane & 15;
  const int kb = lane >> 4;

  int arow = bm + fr; if (arow >= M) arow = M - 1;
  const _Float16* ap = A + (size_t)arow * K + kb * 8;
  const _Float16* bp = Wt + (size_t)(bn + fr) * K + kb * 8;

  f32x4 acc[8] = {};
  for (int k0 = 0; k0 < K; k0 += 32) {
    const f16x8 a = *(const f16x8*)(ap + k0);
    #pragma unroll
    for (int nt = 0; nt < 8; ++nt) {
      const f16x8 b = *(const f16x8*)(bp + (size_t)nt * 16 * K + k0);
      acc[nt] = __builtin_amdgcn_mfma_f32_16x16x32_f16(a, b, acc[nt], 0, 0, 0);
    }
  }
  #pragma unroll
  for (int r = 0; r < 4; ++r) {
    const int row = bm + (lane >> 4) * 4 + r;
    if (row >= M) continue;
    #pragma unroll
    for (int nt = 0; nt < 8; ++nt) {
      const int col = bn + nt * 16 + fr;
      float v = acc[nt][r] + bias[col];
      if (RELU && v < 0.f) v = 0.f;
      C[(size_t)row * N + col] = (_Float16)v;
    }
  }
}

// ---------------- CSR build (by destination; stores SRC node id) ----------------
__global__ __launch_bounds__(256) void count_deg(
    const int* __restrict__ ei, int* __restrict__ deg, int E, int Nn) {
  const int t = blockIdx.x * blockDim.x + threadIdx.x;
  const int ET = E + Nn;
  if (t >= ET) return;
  const int dst = (t < E) ? ei[E + t] : (t - E);
  atomicAdd(&deg[dst], 1);
}

__global__ __launch_bounds__(1024) void scan_deg(
    const int* __restrict__ deg, int* __restrict__ rowptr, int Nn) {
  __shared__ int wsum[16];
  __shared__ int carry_s;
  const int tid = threadIdx.x;
  const int wid = tid >> 6, lane = tid & 63;
  if (tid == 0) { carry_s = 0; rowptr[0] = 0; }
  __syncthreads();
  for (int base = 0; base < Nn; base += 1024) {
    const int i = base + tid;
    int s = (i < Nn) ? deg[i] : 0;
    #pragma unroll
    for (int off = 1; off < 64; off <<= 1) {
      int t = __shfl_up(s, off);
      if (lane >= off) s += t;
    }
    if (lane == 63) wsum[wid] = s;
    __syncthreads();
    if (wid == 0 && lane < 16) {
      int ws = wsum[lane];
      #pragma unroll
      for (int off = 1; off < 16; off <<= 1) {
        int t = __shfl_up(ws, off);
        if (lane >= off) ws += t;
      }
      wsum[lane] = ws;
    }
    __syncthreads();
    const int prefix = (wid > 0 ? wsum[wid - 1] : 0) + carry_s;
    if (i < Nn) rowptr[i + 1] = s + prefix;
    __syncthreads();
    if (tid == 0) carry_s += wsum[15];
    __syncthreads();
  }
}

__global__ __launch_bounds__(256) void fill_csr(
    const int* __restrict__ ei, const int* __restrict__ rowptr,
    int* __restrict__ cursor, int* __restrict__ csr, int E, int Nn) {
  const int t = blockIdx.x * blockDim.x + threadIdx.x;
  const int ET = E + Nn;
  if (t >= ET) return;
  int src, dst;
  if (t < E) { src = ei[t]; dst = ei[E + t]; }
  else { src = t - E; dst = t - E; }
  const int pos = atomicAdd(&cursor[dst], 1);
  csr[rowptr[dst] + pos] = src;
}

// ---------------- graph ranges from sorted batch ----------------
__global__ __launch_bounds__(256) void graph_ranges(
    const int* __restrict__ batch, int* __restrict__ gstart, int Nn, int G) {
  const int n = blockIdx.x * 256 + threadIdx.x;
  if (n > Nn) return;
  if (n == 0) {
    for (int g = 0; g <= batch[0]; ++g) gstart[g] = 0;
  } else if (n == Nn) {
    for (int g = batch[Nn - 1] + 1; g <= G; ++g) gstart[g] = Nn;
  } else {
    const int b = batch[n], bp = batch[n - 1];
    for (int g = bp + 1; g <= b; ++g) gstart[g] = n;
  }
}

// ---------------- fused single-pass GATv2 per-node (xlr stride 512) ----------------
// one wave per node; lane covers channels [4*lane,4*lane+4); head h = lane>>3
// MODE 0: layernorm(relu(agg+bias)) -> fp16 outp ; MODE 1: relu(agg+bias) -> tbuf (no atomics)
template <int MODE>
__global__ __launch_bounds__(256) void node_gat(
    const __half* __restrict__ xlr,
    const int* __restrict__ rowptr, const int* __restrict__ csr,
    const float* __restrict__ att, const float* __restrict__ bias,
    const float* __restrict__ lng, const float* __restrict__ lnb,
    __half* __restrict__ outp, int Nn) {
  int n = (int)((blockIdx.x * (size_t)blockDim.x + threadIdx.x) >> 6);
  const int lane = threadIdx.x & 63;
  if (n >= Nn) return;
  n = __builtin_amdgcn_readfirstlane(n);
  const int r0 = rowptr[n], r1 = rowptr[n + 1];
  const int jm = r1 - 1;
  const half4s* __restrict__ xlv = (const half4s*)xlr;       // row stride XSTR/4 = 128
  float4 xr4;
  {
    const half4s xrh = xlv[(size_t)n * (XSTR / 4) + 64 + lane];   // xr = cols 256-511
    const float2 f01 = __half22float2(xrh.a);
    const float2 f23 = __half22float2(xrh.b);
    xr4 = make_float4(f01.x, f01.y, f23.x, f23.y);
  }
  const float4 at4 = *(const float4*)(att + lane * 4);
  float4 acc = make_float4(0.f, 0.f, 0.f, 0.f);
  float den = 0.f;

  for (int j0 = r0; j0 <= jm; j0 += 8) {
    half4s r[8];
    #pragma unroll
    for (int k = 0; k < 8; ++k) {
      int j = j0 + k; j = j <= jm ? j : jm;
      r[k] = xlv[(size_t)csr[j] * (XSTR / 4) + lane];
    }
    float4 a[8];
    float s[8];
    #pragma unroll
    for (int k = 0; k < 8; ++k) {
      const float2 f01 = __half22float2(r[k].a);
      const float2 f23 = __half22float2(r[k].b);
      a[k] = make_float4(f01.x, f01.y, f23.x, f23.y);
      float v, ss;
      v = a[k].x + xr4.x; v = v >= 0.f ? v : 0.2f * v; ss = v * at4.x;
      v = a[k].y + xr4.y; v = v >= 0.f ? v : 0.2f * v; ss = fmaf(v, at4.y, ss);
      v = a[k].z + xr4.z; v = v >= 0.f ? v : 0.2f * v; ss = fmaf(v, at4.z, ss);
      v = a[k].w + xr4.w; v = v >= 0.f ? v : 0.2f * v; ss = fmaf(v, at4.w, ss);
      s[k] = ss;
    }
    #pragma unroll
    for (int k = 0; k < 8; ++k) {
      s[k] += __shfl_xor(s[k], 1);
      s[k] += __shfl_xor(s[k], 2);
      s[k] += __shfl_xor(s[k], 4);
    }
    float w[8];
    #pragma unroll
    for (int k = 0; k < 8; ++k)
      w[k] = (j0 + k <= jm) ? __expf(s[k] - SCORE_SHIFT) : 0.f;
    #pragma unroll
    for (int k = 0; k < 8; ++k) {
      acc.x = fmaf(w[k], a[k].x, acc.x);
      acc.y = fmaf(w[k], a[k].y, acc.y);
      acc.z = fmaf(w[k], a[k].z, acc.z);
      acc.w = fmaf(w[k], a[k].w, acc.w);
      den += w[k];
    }
  }
  const float inv_d = 1.f / den;
  const float4 bb = *(const float4*)(bias + lane * 4);
  float t0 = fmaf(acc.x, inv_d, bb.x); t0 = t0 > 0.f ? t0 : 0.f;
  float t1 = fmaf(acc.y, inv_d, bb.y); t1 = t1 > 0.f ? t1 : 0.f;
  float t2 = fmaf(acc.z, inv_d, bb.z); t2 = t2 > 0.f ? t2 : 0.f;
  float t3 = fmaf(acc.w, inv_d, bb.w); t3 = t3 > 0.f ? t3 : 0.f;

  if (MODE == 0) {
    float s = t0 + t1 + t2 + t3;
    #pragma unroll
    for (int mm = 1; mm < 64; mm <<= 1) s += __shfl_xor(s, mm);
    const float mu = s * (1.f / HIDDIM);
    const float d0 = t0 - mu, d1 = t1 - mu, d2 = t2 - mu, d3 = t3 - mu;
    float q = d0 * d0 + d1 * d1 + d2 * d2 + d3 * d3;
    #pragma unroll
    for (int mm = 1; mm < 64; mm <<= 1) q += __shfl_xor(q, mm);
    const float inv = rsqrtf(q * (1.f / HIDDIM) + 1e-5f);
    const float4 g4 = *(const float4*)(lng + lane * 4);
    const float4 b4 = *(const float4*)(lnb + lane * 4);
    half4s ho;
    ho.a = __floats2half2_rn(d0 * inv * g4.x + b4.x, d1 * inv * g4.y + b4.y);
    ho.b = __floats2half2_rn(d2 * inv * g4.z + b4.z, d3 * inv * g4.w + b4.w);
    *((half4s*)outp + (size_t)n * (HIDDIM / 4) + lane) = ho;
  } else {
    half4s ho;
    ho.a = __floats2half2_rn(t0, t1);
    ho.b = __floats2half2_rn(t2, t3);
    *((half4s*)outp + (size_t)n * (HIDDIM / 4) + lane) = ho;
  }
}

// ---------------- pool: per-graph contiguous streaming reduction ----------------
__global__ __launch_bounds__(256) void pool_kernel(
    const __half* __restrict__ tbuf, const int* __restrict__ gstart,
    float* __restrict__ pooled) {
  const int g = blockIdx.x, rc = blockIdx.y, ch = threadIdx.x;
  const int n0 = gstart[g], n1 = gstart[g + 1];
  float acc = 0.f;
  for (int n = n0 + rc; n < n1; n += 8)
    acc += __half2float(tbuf[(size_t)n * HIDDIM + ch]);
  atomicAdd(&pooled[g * HIDDIM + ch], acc);
}

// ---------------- head MLP: one block per graph ----------------
__global__ __launch_bounds__(256) void head_kernel(
    const float* __restrict__ pooled, const int* __restrict__ gstart,
    const float* __restrict__ h1w, const float* __restrict__ h1b,
    const float* __restrict__ h2w, const float* __restrict__ h2b,
    float* __restrict__ out, int H1, int OUT) {
  const int g = blockIdx.x;
  __shared__ float P[HIDDIM];
  __shared__ float Hh[128];
  const int tid = threadIdx.x;
  float cnt = (float)(gstart[g + 1] - gstart[g]);
  if (cnt < 1.f) cnt = 1.f;
  P[tid] = pooled[g * HIDDIM + tid] / cnt;
  __syncthreads();
  if (tid < H1) {
    float s = h1b[tid];
    for (int k = 0; k < HIDDIM; ++k) s = fmaf(P[k], h1w[k * H1 + tid], s);
    Hh[tid] = s > 0.f ? s : 0.f;
  }
  __syncthreads();
  if (tid < OUT) {
    float s = h2b[tid];
    for (int k = 0; k < H1; ++k) s = fmaf(Hh[k], h2w[k * OUT + tid], s);
    out[g * OUT + tid] = s;
  }
}

extern "C" void kernel_launch(void* const* d_in, const int* in_sizes, int n_in,
                              void* d_out, int out_size, void* d_ws, size_t ws_size,
                              hipStream_t stream) {
  const float* x = (const float*)d_in[0];
  const int* ei = (const int*)d_in[1];
  const int* batch = (const int*)d_in[2];
  const float* enc_w = (const float*)d_in[3];
  const float* enc_b = (const float*)d_in[4];
  const float* g_wl[2] = {(const float*)d_in[5], (const float*)d_in[11]};
  const float* g_bl[2] = {(const float*)d_in[6], (const float*)d_in[12]};
  const float* g_wr[2] = {(const float*)d_in[7], (const float*)d_in[13]};
  const float* g_br[2] = {(const float*)d_in[8], (const float*)d_in[14]};
  const float* g_att[2] = {(const float*)d_in[9], (const float*)d_in[15]};
  const float* g_bias[2] = {(const float*)d_in[10], (const float*)d_in[16]};
  const float* ln_g = (const float*)d_in[17];
  const float* ln_b = (const float*)d_in[18];
  const float* h1_w = (const float*)d_in[19];
  const float* h1_b = (const float*)d_in[20];
  const float* h2_w = (const float*)d_in[21];
  const float* h2_b = (const float*)d_in[22];
  float* out = (float*)d_out;

  const int N = in_sizes[2];          // 20000
  const int E = in_sizes[1] / 2;      // 320000
  const int DIN = in_sizes[0] / N;    // 128
  const int ET = E + N;
  const int H1 = in_sizes[20];        // 128
  const int OUT = in_sizes[22];       // 2
  const int G = out_size / OUT;       // 16

  char* base = (char*)d_ws;
  const size_t NH = (size_t)N * HIDDIM;
  __half* h16  = (__half*)base;                    // [N][256]
  __half* xlr  = h16 + NH;                         // [N][512]  (xl | xr)
  __half* tbuf = xlr + NH * 2;                     // [N][256]
  __half* x16  = tbuf + NH;                        // [N][DIN]
  __half* wtE  = x16 + (size_t)N * DIN;            // [256][DIN]
  __half* wtC0 = wtE + (size_t)HIDDIM * DIN;       // [512][256]
  __half* wtC1 = wtC0 + (size_t)XSTR * HIDDIM;     // [512][256]
  float* biasC0 = (float*)(wtC1 + (size_t)XSTR * HIDDIM);
  float* biasC1 = biasC0 + XSTR;
  float* pooled = biasC1 + XSTR;                   // [G][256]
  int* gstart = (int*)(pooled + (size_t)G * HIDDIM);  // [G+1]
  int* deg    = gstart + (G + 1);
  int* rowptr = deg + N;
  int* cursor = rowptr + (N + 1);
  int* csr    = cursor + N;

  const dim3 blk(256);
  const int eb = (ET + 255) / 256;
  const int nb = (N + 3) / 4;
  const dim3 enc_grid(HIDDIM / 128, (N + 63) / 64);
  const dim3 cmb_grid(XSTR / 128, (N + 63) / 64);

  // CSR build + graph ranges (graph identical for both layers)
  hipMemsetAsync(deg, 0, (size_t)N * sizeof(int), stream);
  hipMemsetAsync(cursor, 0, (size_t)N * sizeof(int), stream);
  hipMemsetAsync(pooled, 0, (size_t)G * HIDDIM * sizeof(float), stream);
  count_deg<<<eb, blk, 0, stream>>>(ei, deg, E, N);
  scan_deg<<<1, 1024, 0, stream>>>(deg, rowptr, N);
  fill_csr<<<eb, blk, 0, stream>>>(ei, rowptr, cursor, csr, E, N);
  graph_ranges<<<(N + 256) / 256, blk, 0, stream>>>(batch, gstart, N, G);

  // weight/input conversion (merged launches)
  cvt_f2h<<<(N * DIN + 255) / 256, blk, 0, stream>>>(x, x16, N * DIN);
  cvt_transpose<<<(DIN * HIDDIM + 255) / 256, blk, 0, stream>>>(enc_w, wtE, DIN, HIDDIM);
  cvt_transpose4<<<dim3((HIDDIM * HIDDIM + 255) / 256, 4), blk, 0, stream>>>(
      g_wl[0], g_wr[0], g_wl[1], g_wr[1],
      wtC0, wtC0 + (size_t)HIDDIM * HIDDIM, wtC1, wtC1 + (size_t)HIDDIM * HIDDIM);
  concat_biases<<<(2 * XSTR + 255) / 256, blk, 0, stream>>>(
      g_bl[0], g_br[0], g_bl[1], g_br[1], biasC0, biasC1);

  // encoder: h16 = relu(x @ enc_w + enc_b)
  gemm_mfma<1><<<enc_grid, blk, 0, stream>>>(
      (const _Float16*)x16, (const _Float16*)wtE, enc_b, (_Float16*)h16, N, HIDDIM, DIN);

  for (int L = 0; L < 2; ++L) {
    const __half* wtC = (L == 0) ? wtC0 : wtC1;
    const float* bC = (L == 0) ? biasC0 : biasC1;
    gemm_mfma<0><<<cmb_grid, blk, 0, stream>>>(
        (const _Float16*)h16, (const _Float16*)wtC, bC, (_Float16*)xlr, N, XSTR, HIDDIM);
    if (L == 0) {
      node_gat<0><<<nb, blk, 0, stream>>>(xlr, rowptr, csr, g_att[0], g_bias[0],
                                          ln_g, ln_b, h16, N);
    } else {
      node_gat<1><<<nb, blk, 0, stream>>>(xlr, rowptr, csr, g_att[1], g_bias[1],
                                          nullptr, nullptr, tbuf, N);
      pool_kernel<<<dim3(G, 8), blk, 0, stream>>>(tbuf, gstart, pooled);
    }
  }
  head_kernel<<<G, blk, 0, stream>>>(pooled, gstart, h1_w, h1_b, h2_w, h2_b, out, H1, OUT);
}

// Round 16
// 296.427 us; speedup vs baseline: 2.4771x; 1.0719x over previous
//
#include <hip/hip_runtime.h>
#include <hip/hip_fp16.h>

#define HIDDIM 256
#define NHEADS 8
#define SCORE_SHIFT 4.0f
#define XSTR 512   // xlr row stride (xl cols 0-255, xr cols 256-511)

struct __attribute__((aligned(8))) half4s { __half2 a, b; };

typedef _Float16 f16x8 __attribute__((ext_vector_type(8)));
typedef float f32x4 __attribute__((ext_vector_type(4)));

// ---------------- converts ----------------
__global__ __launch_bounds__(256) void cvt_f2h(
    const float* __restrict__ in, __half* __restrict__ out, int n) {
  const int i = blockIdx.x * 256 + threadIdx.x;
  if (i < n) out[i] = __float2half(in[i]);
}

// in [K][N] fp32 -> out [N][K] fp16 (transposed)
__global__ __launch_bounds__(256) void cvt_transpose(
    const float* __restrict__ in, __half* __restrict__ out, int K, int N) {
  const int idx = blockIdx.x * 256 + threadIdx.x;
  if (idx >= K * N) return;
  const int n = idx / K, k = idx - n * K;
  out[idx] = __float2half(in[(size_t)k * N + n]);
}

// 4 HIDxHID transposes in one launch (blockIdx.y selects)
__global__ __launch_bounds__(256) void cvt_transpose4(
    const float* __restrict__ w0, const float* __restrict__ w1,
    const float* __restrict__ w2, const float* __restrict__ w3,
    __half* __restrict__ o0, __half* __restrict__ o1,
    __half* __restrict__ o2, __half* __restrict__ o3) {
  const float* in; __half* out;
  switch (blockIdx.y) {
    case 0: in = w0; out = o0; break;
    case 1: in = w1; out = o1; break;
    case 2: in = w2; out = o2; break;
    default: in = w3; out = o3; break;
  }
  const int idx = blockIdx.x * 256 + threadIdx.x;
  if (idx >= HIDDIM * HIDDIM) return;
  const int n = idx / HIDDIM, k = idx - n * HIDDIM;
  out[idx] = __float2half(in[(size_t)k * HIDDIM + n]);
}

// both layers' [bl|br] concats in one launch: 2 x 512 floats
__global__ __launch_bounds__(256) void concat_biases(
    const float* __restrict__ bl0, const float* __restrict__ br0,
    const float* __restrict__ bl1, const float* __restrict__ br1,
    float* __restrict__ o0, float* __restrict__ o1) {
  const int i = blockIdx.x * 256 + threadIdx.x;
  if (i >= 2 * XSTR) return;
  const int layer = i >> 9, pos = i & (XSTR - 1);
  const float* bl = layer ? bl1 : bl0;
  const float* br = layer ? br1 : br0;
  float v = (pos < HIDDIM) ? bl[pos] : br[pos - HIDDIM];
  (layer ? o1 : o0)[pos] = v;
}

// ---------------- MFMA GEMM (compile-time K, fully unrolled) ----------------
// block = 128 rows x 128 cols (4 waves); wave = 32 rows x 128 cols
// = 16 MFMA per 32-k step, 2 A-loads + 8 B-loads. Full unroll over KT.
template <int RELU, int KT>
__global__ __launch_bounds__(256) void gemm_mfma(
    const _Float16* __restrict__ A, const _Float16* __restrict__ Wt,
    const float* __restrict__ bias, _Float16* __restrict__ C,
    int M, int N) {
  const int wv = threadIdx.x >> 6;
  const int lane = threadIdx.x & 63;
  const int bn = blockIdx.x * 128;
  const int bm = blockIdx.y * 128 + wv * 32;
  const int fr = lane & 15;
  const int kb = lane >> 4;

  int ar0 = bm + fr;      if (ar0 >= M) ar0 = M - 1;
  int ar1 = bm + 16 + fr; if (ar1 >= M) ar1 = M - 1;
  const _Float16* ap0 = A + (size_t)ar0 * KT + kb * 8;
  const _Float16* ap1 = A + (size_t)ar1 * KT + kb * 8;
  const _Float16* bp  = Wt + (size_t)(bn + fr) * KT + kb * 8;

  f32x4 acc[2][8] = {};
  #pragma unroll
  for (int k0 = 0; k0 < KT; k0 += 32) {
    const f16x8 a0 = *(const f16x8*)(ap0 + k0);
    const f16x8 a1 = *(const f16x8*)(ap1 + k0);
    #pragma unroll
    for (int nt = 0; nt < 8; ++nt) {
      const f16x8 b = *(const f16x8*)(bp + (size_t)nt * 16 * KT + k0);
      acc[0][nt] = __builtin_amdgcn_mfma_f32_16x16x32_f16(a0, b, acc[0][nt], 0, 0, 0);
      acc[1][nt] = __builtin_amdgcn_mfma_f32_16x16x32_f16(a1, b, acc[1][nt], 0, 0, 0);
    }
  }
  #pragma unroll
  for (int g = 0; g < 2; ++g) {
    #pragma unroll
    for (int r = 0; r < 4; ++r) {
      const int row = bm + g * 16 + (lane >> 4) * 4 + r;
      if (row >= M) continue;
      #pragma unroll
      for (int nt = 0; nt < 8; ++nt) {
        const int col = bn + nt * 16 + fr;
        float v = acc[g][nt][r] + bias[col];
        if (RELU && v < 0.f) v = 0.f;
        C[(size_t)row * N + col] = (_Float16)v;
      }
    }
  }
}

// ---------------- CSR build (by destination; stores SRC node id) ----------------
__global__ __launch_bounds__(256) void count_deg(
    const int* __restrict__ ei, int* __restrict__ deg, int E, int Nn) {
  const int t = blockIdx.x * blockDim.x + threadIdx.x;
  const int ET = E + Nn;
  if (t >= ET) return;
  const int dst = (t < E) ? ei[E + t] : (t - E);
  atomicAdd(&deg[dst], 1);
}

__global__ __launch_bounds__(1024) void scan_deg(
    const int* __restrict__ deg, int* __restrict__ rowptr, int Nn) {
  __shared__ int wsum[16];
  __shared__ int carry_s;
  const int tid = threadIdx.x;
  const int wid = tid >> 6, lane = tid & 63;
  if (tid == 0) { carry_s = 0; rowptr[0] = 0; }
  __syncthreads();
  for (int base = 0; base < Nn; base += 1024) {
    const int i = base + tid;
    int s = (i < Nn) ? deg[i] : 0;
    #pragma unroll
    for (int off = 1; off < 64; off <<= 1) {
      int t = __shfl_up(s, off);
      if (lane >= off) s += t;
    }
    if (lane == 63) wsum[wid] = s;
    __syncthreads();
    if (wid == 0 && lane < 16) {
      int ws = wsum[lane];
      #pragma unroll
      for (int off = 1; off < 16; off <<= 1) {
        int t = __shfl_up(ws, off);
        if (lane >= off) ws += t;
      }
      wsum[lane] = ws;
    }
    __syncthreads();
    const int prefix = (wid > 0 ? wsum[wid - 1] : 0) + carry_s;
    if (i < Nn) rowptr[i + 1] = s + prefix;
    __syncthreads();
    if (tid == 0) carry_s += wsum[15];
    __syncthreads();
  }
}

__global__ __launch_bounds__(256) void fill_csr(
    const int* __restrict__ ei, const int* __restrict__ rowptr,
    int* __restrict__ cursor, int* __restrict__ csr, int E, int Nn) {
  const int t = blockIdx.x * blockDim.x + threadIdx.x;
  const int ET = E + Nn;
  if (t >= ET) return;
  int src, dst;
  if (t < E) { src = ei[t]; dst = ei[E + t]; }
  else { src = t - E; dst = t - E; }
  const int pos = atomicAdd(&cursor[dst], 1);
  csr[rowptr[dst] + pos] = src;
}

// ---------------- graph ranges from sorted batch ----------------
__global__ __launch_bounds__(256) void graph_ranges(
    const int* __restrict__ batch, int* __restrict__ gstart, int Nn, int G) {
  const int n = blockIdx.x * 256 + threadIdx.x;
  if (n > Nn) return;
  if (n == 0) {
    for (int g = 0; g <= batch[0]; ++g) gstart[g] = 0;
  } else if (n == Nn) {
    for (int g = batch[Nn - 1] + 1; g <= G; ++g) gstart[g] = Nn;
  } else {
    const int b = batch[n], bp = batch[n - 1];
    for (int g = bp + 1; g <= b; ++g) gstart[g] = n;
  }
}

// ---------------- fused single-pass GATv2 per-node (xlr stride 512) ----------------
template <int MODE>
__global__ __launch_bounds__(256) void node_gat(
    const __half* __restrict__ xlr,
    const int* __restrict__ rowptr, const int* __restrict__ csr,
    const float* __restrict__ att, const float* __restrict__ bias,
    const float* __restrict__ lng, const float* __restrict__ lnb,
    __half* __restrict__ outp, int Nn) {
  int n = (int)((blockIdx.x * (size_t)blockDim.x + threadIdx.x) >> 6);
  const int lane = threadIdx.x & 63;
  if (n >= Nn) return;
  n = __builtin_amdgcn_readfirstlane(n);
  const int r0 = rowptr[n], r1 = rowptr[n + 1];
  const int jm = r1 - 1;
  const half4s* __restrict__ xlv = (const half4s*)xlr;       // row stride XSTR/4 = 128
  float4 xr4;
  {
    const half4s xrh = xlv[(size_t)n * (XSTR / 4) + 64 + lane];   // xr = cols 256-511
    const float2 f01 = __half22float2(xrh.a);
    const float2 f23 = __half22float2(xrh.b);
    xr4 = make_float4(f01.x, f01.y, f23.x, f23.y);
  }
  const float4 at4 = *(const float4*)(att + lane * 4);
  float4 acc = make_float4(0.f, 0.f, 0.f, 0.f);
  float den = 0.f;

  for (int j0 = r0; j0 <= jm; j0 += 8) {
    half4s r[8];
    #pragma unroll
    for (int k = 0; k < 8; ++k) {
      int j = j0 + k; j = j <= jm ? j : jm;
      r[k] = xlv[(size_t)csr[j] * (XSTR / 4) + lane];
    }
    float4 a[8];
    float s[8];
    #pragma unroll
    for (int k = 0; k < 8; ++k) {
      const float2 f01 = __half22float2(r[k].a);
      const float2 f23 = __half22float2(r[k].b);
      a[k] = make_float4(f01.x, f01.y, f23.x, f23.y);
      float v, ss;
      v = a[k].x + xr4.x; v = v >= 0.f ? v : 0.2f * v; ss = v * at4.x;
      v = a[k].y + xr4.y; v = v >= 0.f ? v : 0.2f * v; ss = fmaf(v, at4.y, ss);
      v = a[k].z + xr4.z; v = v >= 0.f ? v : 0.2f * v; ss = fmaf(v, at4.z, ss);
      v = a[k].w + xr4.w; v = v >= 0.f ? v : 0.2f * v; ss = fmaf(v, at4.w, ss);
      s[k] = ss;
    }
    #pragma unroll
    for (int k = 0; k < 8; ++k) {
      s[k] += __shfl_xor(s[k], 1);
      s[k] += __shfl_xor(s[k], 2);
      s[k] += __shfl_xor(s[k], 4);
    }
    float w[8];
    #pragma unroll
    for (int k = 0; k < 8; ++k)
      w[k] = (j0 + k <= jm) ? __expf(s[k] - SCORE_SHIFT) : 0.f;
    #pragma unroll
    for (int k = 0; k < 8; ++k) {
      acc.x = fmaf(w[k], a[k].x, acc.x);
      acc.y = fmaf(w[k], a[k].y, acc.y);
      acc.z = fmaf(w[k], a[k].z, acc.z);
      acc.w = fmaf(w[k], a[k].w, acc.w);
      den += w[k];
    }
  }
  const float inv_d = 1.f / den;
  const float4 bb = *(const float4*)(bias + lane * 4);
  float t0 = fmaf(acc.x, inv_d, bb.x); t0 = t0 > 0.f ? t0 : 0.f;
  float t1 = fmaf(acc.y, inv_d, bb.y); t1 = t1 > 0.f ? t1 : 0.f;
  float t2 = fmaf(acc.z, inv_d, bb.z); t2 = t2 > 0.f ? t2 : 0.f;
  float t3 = fmaf(acc.w, inv_d, bb.w); t3 = t3 > 0.f ? t3 : 0.f;

  if (MODE == 0) {
    float s = t0 + t1 + t2 + t3;
    #pragma unroll
    for (int mm = 1; mm < 64; mm <<= 1) s += __shfl_xor(s, mm);
    const float mu = s * (1.f / HIDDIM);
    const float d0 = t0 - mu, d1 = t1 - mu, d2 = t2 - mu, d3 = t3 - mu;
    float q = d0 * d0 + d1 * d1 + d2 * d2 + d3 * d3;
    #pragma unroll
    for (int mm = 1; mm < 64; mm <<= 1) q += __shfl_xor(q, mm);
    const float inv = rsqrtf(q * (1.f / HIDDIM) + 1e-5f);
    const float4 g4 = *(const float4*)(lng + lane * 4);
    const float4 b4 = *(const float4*)(lnb + lane * 4);
    half4s ho;
    ho.a = __floats2half2_rn(d0 * inv * g4.x + b4.x, d1 * inv * g4.y + b4.y);
    ho.b = __floats2half2_rn(d2 * inv * g4.z + b4.z, d3 * inv * g4.w + b4.w);
    *((half4s*)outp + (size_t)n * (HIDDIM / 4) + lane) = ho;
  } else {
    half4s ho;
    ho.a = __floats2half2_rn(t0, t1);
    ho.b = __floats2half2_rn(t2, t3);
    *((half4s*)outp + (size_t)n * (HIDDIM / 4) + lane) = ho;
  }
}

// ---------------- pool: per-graph contiguous streaming reduction ----------------
__global__ __launch_bounds__(256) void pool_kernel(
    const __half* __restrict__ tbuf, const int* __restrict__ gstart,
    float* __restrict__ pooled) {
  const int g = blockIdx.x, rc = blockIdx.y, ch = threadIdx.x;
  const int n0 = gstart[g], n1 = gstart[g + 1];
  float acc = 0.f;
  for (int n = n0 + rc; n < n1; n += 8)
    acc += __half2float(tbuf[(size_t)n * HIDDIM + ch]);
  atomicAdd(&pooled[g * HIDDIM + ch], acc);
}

// ---------------- head MLP: one block per graph ----------------
__global__ __launch_bounds__(256) void head_kernel(
    const float* __restrict__ pooled, const int* __restrict__ gstart,
    const float* __restrict__ h1w, const float* __restrict__ h1b,
    const float* __restrict__ h2w, const float* __restrict__ h2b,
    float* __restrict__ out, int H1, int OUT) {
  const int g = blockIdx.x;
  __shared__ float P[HIDDIM];
  __shared__ float Hh[128];
  const int tid = threadIdx.x;
  float cnt = (float)(gstart[g + 1] - gstart[g]);
  if (cnt < 1.f) cnt = 1.f;
  P[tid] = pooled[g * HIDDIM + tid] / cnt;
  __syncthreads();
  if (tid < H1) {
    float s = h1b[tid];
    for (int k = 0; k < HIDDIM; ++k) s = fmaf(P[k], h1w[k * H1 + tid], s);
    Hh[tid] = s > 0.f ? s : 0.f;
  }
  __syncthreads();
  if (tid < OUT) {
    float s = h2b[tid];
    for (int k = 0; k < H1; ++k) s = fmaf(Hh[k], h2w[k * OUT + tid], s);
    out[g * OUT + tid] = s;
  }
}

extern "C" void kernel_launch(void* const* d_in, const int* in_sizes, int n_in,
                              void* d_out, int out_size, void* d_ws, size_t ws_size,
                              hipStream_t stream) {
  const float* x = (const float*)d_in[0];
  const int* ei = (const int*)d_in[1];
  const int* batch = (const int*)d_in[2];
  const float* enc_w = (const float*)d_in[3];
  const float* enc_b = (const float*)d_in[4];
  const float* g_wl[2] = {(const float*)d_in[5], (const float*)d_in[11]};
  const float* g_bl[2] = {(const float*)d_in[6], (const float*)d_in[12]};
  const float* g_wr[2] = {(const float*)d_in[7], (const float*)d_in[13]};
  const float* g_br[2] = {(const float*)d_in[8], (const float*)d_in[14]};
  const float* g_att[2] = {(const float*)d_in[9], (const float*)d_in[15]};
  const float* g_bias[2] = {(const float*)d_in[10], (const float*)d_in[16]};
  const float* ln_g = (const float*)d_in[17];
  const float* ln_b = (const float*)d_in[18];
  const float* h1_w = (const float*)d_in[19];
  const float* h1_b = (const float*)d_in[20];
  const float* h2_w = (const float*)d_in[21];
  const float* h2_b = (const float*)d_in[22];
  float* out = (float*)d_out;

  const int N = in_sizes[2];          // 20000
  const int E = in_sizes[1] / 2;      // 320000
  const int DIN = in_sizes[0] / N;    // 128
  const int ET = E + N;
  const int H1 = in_sizes[20];        // 128
  const int OUT = in_sizes[22];       // 2
  const int G = out_size / OUT;       // 16

  char* base = (char*)d_ws;
  const size_t NH = (size_t)N * HIDDIM;
  __half* h16  = (__half*)base;                    // [N][256]
  __half* xlr  = h16 + NH;                         // [N][512]  (xl | xr)
  __half* tbuf = xlr + NH * 2;                     // [N][256]
  __half* x16  = tbuf + NH;                        // [N][DIN]
  __half* wtE  = x16 + (size_t)N * DIN;            // [256][DIN]
  __half* wtC0 = wtE + (size_t)HIDDIM * DIN;       // [512][256]
  __half* wtC1 = wtC0 + (size_t)XSTR * HIDDIM;     // [512][256]
  float* biasC0 = (float*)(wtC1 + (size_t)XSTR * HIDDIM);
  float* biasC1 = biasC0 + XSTR;
  float* pooled = biasC1 + XSTR;                   // [G][256]
  int* gstart = (int*)(pooled + (size_t)G * HIDDIM);  // [G+1]
  int* deg    = gstart + (G + 1);
  int* rowptr = deg + N;
  int* cursor = rowptr + (N + 1);
  int* csr    = cursor + N;

  const dim3 blk(256);
  const int eb = (ET + 255) / 256;
  const int nb = (N + 3) / 4;
  const dim3 enc_grid(HIDDIM / 128, (N + 127) / 128);
  const dim3 cmb_grid(XSTR / 128, (N + 127) / 128);

  // CSR build + graph ranges (graph identical for both layers)
  hipMemsetAsync(deg, 0, (size_t)N * sizeof(int), stream);
  hipMemsetAsync(cursor, 0, (size_t)N * sizeof(int), stream);
  hipMemsetAsync(pooled, 0, (size_t)G * HIDDIM * sizeof(float), stream);
  count_deg<<<eb, blk, 0, stream>>>(ei, deg, E, N);
  scan_deg<<<1, 1024, 0, stream>>>(deg, rowptr, N);
  fill_csr<<<eb, blk, 0, stream>>>(ei, rowptr, cursor, csr, E, N);
  graph_ranges<<<(N + 256) / 256, blk, 0, stream>>>(batch, gstart, N, G);

  // weight/input conversion (merged launches)
  cvt_f2h<<<(N * DIN + 255) / 256, blk, 0, stream>>>(x, x16, N * DIN);
  cvt_transpose<<<(DIN * HIDDIM + 255) / 256, blk, 0, stream>>>(enc_w, wtE, DIN, HIDDIM);
  cvt_transpose4<<<dim3((HIDDIM * HIDDIM + 255) / 256, 4), blk, 0, stream>>>(
      g_wl[0], g_wr[0], g_wl[1], g_wr[1],
      wtC0, wtC0 + (size_t)HIDDIM * HIDDIM, wtC1, wtC1 + (size_t)HIDDIM * HIDDIM);
  concat_biases<<<(2 * XSTR + 255) / 256, blk, 0, stream>>>(
      g_bl[0], g_br[0], g_bl[1], g_br[1], biasC0, biasC1);

  // encoder: h16 = relu(x @ enc_w + enc_b)   (KT = 128)
  gemm_mfma<1, 128><<<enc_grid, blk, 0, stream>>>(
      (const _Float16*)x16, (const _Float16*)wtE, enc_b, (_Float16*)h16, N, HIDDIM);

  for (int L = 0; L < 2; ++L) {
    const __half* wtC = (L == 0) ? wtC0 : wtC1;
    const float* bC = (L == 0) ? biasC0 : biasC1;
    gemm_mfma<0, 256><<<cmb_grid, blk, 0, stream>>>(
        (const _Float16*)h16, (const _Float16*)wtC, bC, (_Float16*)xlr, N, XSTR);
    if (L == 0) {
      node_gat<0><<<nb, blk, 0, stream>>>(xlr, rowptr, csr, g_att[0], g_bias[0],
                                          ln_g, ln_b, h16, N);
    } else {
      node_gat<1><<<nb, blk, 0, stream>>>(xlr, rowptr, csr, g_att[1], g_bias[1],
                                          nullptr, nullptr, tbuf, N);
      pool_kernel<<<dim3(G, 8), blk, 0, stream>>>(tbuf, gstart, pooled);
    }
  }
  head_kernel<<<G, blk, 0, stream>>>(pooled, gstart, h1_w, h1_b, h2_w, h2_b, out, H1, OUT);
}

// Round 17
// 245.109 us; speedup vs baseline: 2.9957x; 1.2094x over previous
//
#include <hip/hip_runtime.h>
#include <hip/hip_fp16.h>

#define HIDDIM 256
#define NHEADS 8
#define SCORE_SHIFT 4.0f
#define XSTR 512   // xlr row stride (xl cols 0-255, xr cols 256-511)
#define BPAD 40    // padded LDS row stride (halves) for B tile

struct __attribute__((aligned(8))) half4s { __half2 a, b; };

typedef _Float16 f16x8 __attribute__((ext_vector_type(8)));
typedef float f32x4 __attribute__((ext_vector_type(4)));

// ---------------- converts ----------------
__global__ __launch_bounds__(256) void cvt_f2h(
    const float* __restrict__ in, __half* __restrict__ out, int n) {
  const int i = blockIdx.x * 256 + threadIdx.x;
  if (i < n) out[i] = __float2half(in[i]);
}

// in [K][N] fp32 -> out [N][K] fp16 (transposed)
__global__ __launch_bounds__(256) void cvt_transpose(
    const float* __restrict__ in, __half* __restrict__ out, int K, int N) {
  const int idx = blockIdx.x * 256 + threadIdx.x;
  if (idx >= K * N) return;
  const int n = idx / K, k = idx - n * K;
  out[idx] = __float2half(in[(size_t)k * N + n]);
}

// 4 HIDxHID transposes in one launch (blockIdx.y selects)
__global__ __launch_bounds__(256) void cvt_transpose4(
    const float* __restrict__ w0, const float* __restrict__ w1,
    const float* __restrict__ w2, const float* __restrict__ w3,
    __half* __restrict__ o0, __half* __restrict__ o1,
    __half* __restrict__ o2, __half* __restrict__ o3) {
  const float* in; __half* out;
  switch (blockIdx.y) {
    case 0: in = w0; out = o0; break;
    case 1: in = w1; out = o1; break;
    case 2: in = w2; out = o2; break;
    default: in = w3; out = o3; break;
  }
  const int idx = blockIdx.x * 256 + threadIdx.x;
  if (idx >= HIDDIM * HIDDIM) return;
  const int n = idx / HIDDIM, k = idx - n * HIDDIM;
  out[idx] = __float2half(in[(size_t)k * HIDDIM + n]);
}

// both layers' [bl|br] concats in one launch: 2 x 512 floats
__global__ __launch_bounds__(256) void concat_biases(
    const float* __restrict__ bl0, const float* __restrict__ br0,
    const float* __restrict__ bl1, const float* __restrict__ br1,
    float* __restrict__ o0, float* __restrict__ o1) {
  const int i = blockIdx.x * 256 + threadIdx.x;
  if (i >= 2 * XSTR) return;
  const int layer = i >> 9, pos = i & (XSTR - 1);
  const float* bl = layer ? bl1 : bl0;
  const float* br = layer ? br1 : br0;
  float v = (pos < HIDDIM) ? bl[pos] : br[pos - HIDDIM];
  (layer ? o1 : o0)[pos] = v;
}

// ---------------- MFMA GEMM with LDS-staged B tile ----------------
// block = 128 rows x 128 cols (4 waves, wave = 32 rows x 128 cols).
// Per 32-k step: 256 threads cooperatively stage the 128x32 B-tile into LDS
// (padded stride 40 halves -> 2-way-free bank pattern), then 16 MFMA/wave.
// A loads issued BEFORE the staging barriers so their latency hides.
template <int RELU, int KT>
__global__ __launch_bounds__(256) void gemm_mfma(
    const _Float16* __restrict__ A, const _Float16* __restrict__ Wt,
    const float* __restrict__ bias, _Float16* __restrict__ C,
    int M, int N) {
  __shared__ _Float16 Bs[128 * BPAD];
  const int tid = threadIdx.x;
  const int wv = tid >> 6;
  const int lane = tid & 63;
  const int bn = blockIdx.x * 128;
  const int bm = blockIdx.y * 128 + wv * 32;
  const int fr = lane & 15;
  const int kb = lane >> 4;

  int ar0 = bm + fr;      if (ar0 >= M) ar0 = M - 1;
  int ar1 = bm + 16 + fr; if (ar1 >= M) ar1 = M - 1;
  const _Float16* ap0 = A + (size_t)ar0 * KT + kb * 8;
  const _Float16* ap1 = A + (size_t)ar1 * KT + kb * 8;

  // staging mapping: thread covers col c, 8-half chunk ch (two rounds: cols 0-63, 64-127)
  const int sc = tid >> 2;            // 0..63
  const int sch = (tid & 3) * 8;      // 0,8,16,24

  f32x4 acc[2][8] = {};
  #pragma unroll
  for (int k0 = 0; k0 < KT; k0 += 32) {
    // issue A loads + B staging loads first (latency overlaps barriers)
    const f16x8 a0 = *(const f16x8*)(ap0 + k0);
    const f16x8 a1 = *(const f16x8*)(ap1 + k0);
    const f16x8 s0 = *(const f16x8*)(Wt + (size_t)(bn + sc) * KT + k0 + sch);
    const f16x8 s1 = *(const f16x8*)(Wt + (size_t)(bn + 64 + sc) * KT + k0 + sch);
    __syncthreads();   // prior step's reads complete before overwrite
    *(f16x8*)(Bs + sc * BPAD + sch) = s0;
    *(f16x8*)(Bs + (64 + sc) * BPAD + sch) = s1;
    __syncthreads();   // tile ready
    #pragma unroll
    for (int nt = 0; nt < 8; ++nt) {
      const f16x8 b = *(const f16x8*)(Bs + (nt * 16 + fr) * BPAD + kb * 8);
      acc[0][nt] = __builtin_amdgcn_mfma_f32_16x16x32_f16(a0, b, acc[0][nt], 0, 0, 0);
      acc[1][nt] = __builtin_amdgcn_mfma_f32_16x16x32_f16(a1, b, acc[1][nt], 0, 0, 0);
    }
  }
  #pragma unroll
  for (int g = 0; g < 2; ++g) {
    #pragma unroll
    for (int r = 0; r < 4; ++r) {
      const int row = bm + g * 16 + (lane >> 4) * 4 + r;
      if (row >= M) continue;
      #pragma unroll
      for (int nt = 0; nt < 8; ++nt) {
        const int col = bn + nt * 16 + fr;
        float v = acc[g][nt][r] + bias[col];
        if (RELU && v < 0.f) v = 0.f;
        C[(size_t)row * N + col] = (_Float16)v;
      }
    }
  }
}

// ---------------- CSR build (by destination; stores SRC node id) ----------------
__global__ __launch_bounds__(256) void count_deg(
    const int* __restrict__ ei, int* __restrict__ deg, int E, int Nn) {
  const int t = blockIdx.x * blockDim.x + threadIdx.x;
  const int ET = E + Nn;
  if (t >= ET) return;
  const int dst = (t < E) ? ei[E + t] : (t - E);
  atomicAdd(&deg[dst], 1);
}

// fast single-block scan: CH elems/thread serial prefix + wave scan + 16-scan
__global__ __launch_bounds__(1024) void scan_deg(
    const int* __restrict__ deg, int* __restrict__ rowptr, int Nn) {
  const int tid = threadIdx.x;
  const int wid = tid >> 6, lane = tid & 63;
  const int CH = (Nn + 1023) >> 10;   // assumed <= 32
  const int base = tid * CH;
  int s[32];
  int run = 0;
  #pragma unroll
  for (int i = 0; i < 32; ++i) {
    if (i < CH) {
      const int idx = base + i;
      const int v = (idx < Nn) ? deg[idx] : 0;
      run += v;
    }
    s[i] = run;
  }
  int tot = run;
  #pragma unroll
  for (int off = 1; off < 64; off <<= 1) {
    int t = __shfl_up(tot, off);
    if (lane >= off) tot += t;
  }
  __shared__ int wsum[16];
  __shared__ int wpre[16];
  if (lane == 63) wsum[wid] = tot;
  __syncthreads();
  if (tid < 16) {
    int ws = wsum[tid];
    #pragma unroll
    for (int off = 1; off < 16; off <<= 1) {
      int t = __shfl_up(ws, off);
      if (tid >= off) ws += t;
    }
    wpre[tid] = ws;
  }
  __syncthreads();
  const int excl = (wid ? wpre[wid - 1] : 0) + (tot - run);
  #pragma unroll
  for (int i = 0; i < 32; ++i) {
    if (i < CH) {
      const int idx = base + i;
      if (idx < Nn) rowptr[idx + 1] = excl + s[i];
    }
  }
  if (tid == 0) rowptr[0] = 0;
}

__global__ __launch_bounds__(256) void fill_csr(
    const int* __restrict__ ei, const int* __restrict__ rowptr,
    int* __restrict__ cursor, int* __restrict__ csr, int E, int Nn) {
  const int t = blockIdx.x * blockDim.x + threadIdx.x;
  const int ET = E + Nn;
  if (t >= ET) return;
  int src, dst;
  if (t < E) { src = ei[t]; dst = ei[E + t]; }
  else { src = t - E; dst = t - E; }
  const int pos = atomicAdd(&cursor[dst], 1);
  csr[rowptr[dst] + pos] = src;
}

// ---------------- graph ranges from sorted batch ----------------
__global__ __launch_bounds__(256) void graph_ranges(
    const int* __restrict__ batch, int* __restrict__ gstart, int Nn, int G) {
  const int n = blockIdx.x * 256 + threadIdx.x;
  if (n > Nn) return;
  if (n == 0) {
    for (int g = 0; g <= batch[0]; ++g) gstart[g] = 0;
  } else if (n == Nn) {
    for (int g = batch[Nn - 1] + 1; g <= G; ++g) gstart[g] = Nn;
  } else {
    const int b = batch[n], bp = batch[n - 1];
    for (int g = bp + 1; g <= b; ++g) gstart[g] = n;
  }
}

// ---------------- fused single-pass GATv2 per-node (xlr stride 512) ----------------
template <int MODE>
__global__ __launch_bounds__(256) void node_gat(
    const __half* __restrict__ xlr,
    const int* __restrict__ rowptr, const int* __restrict__ csr,
    const float* __restrict__ att, const float* __restrict__ bias,
    const float* __restrict__ lng, const float* __restrict__ lnb,
    __half* __restrict__ outp, int Nn) {
  int n = (int)((blockIdx.x * (size_t)blockDim.x + threadIdx.x) >> 6);
  const int lane = threadIdx.x & 63;
  if (n >= Nn) return;
  n = __builtin_amdgcn_readfirstlane(n);
  const int r0 = rowptr[n], r1 = rowptr[n + 1];
  const int jm = r1 - 1;
  const half4s* __restrict__ xlv = (const half4s*)xlr;       // row stride XSTR/4 = 128
  float4 xr4;
  {
    const half4s xrh = xlv[(size_t)n * (XSTR / 4) + 64 + lane];   // xr = cols 256-511
    const float2 f01 = __half22float2(xrh.a);
    const float2 f23 = __half22float2(xrh.b);
    xr4 = make_float4(f01.x, f01.y, f23.x, f23.y);
  }
  const float4 at4 = *(const float4*)(att + lane * 4);
  float4 acc = make_float4(0.f, 0.f, 0.f, 0.f);
  float den = 0.f;

  for (int j0 = r0; j0 <= jm; j0 += 8) {
    half4s r[8];
    #pragma unroll
    for (int k = 0; k < 8; ++k) {
      int j = j0 + k; j = j <= jm ? j : jm;
      r[k] = xlv[(size_t)csr[j] * (XSTR / 4) + lane];
    }
    float4 a[8];
    float s[8];
    #pragma unroll
    for (int k = 0; k < 8; ++k) {
      const float2 f01 = __half22float2(r[k].a);
      const float2 f23 = __half22float2(r[k].b);
      a[k] = make_float4(f01.x, f01.y, f23.x, f23.y);
      float v, ss;
      v = a[k].x + xr4.x; v = v >= 0.f ? v : 0.2f * v; ss = v * at4.x;
      v = a[k].y + xr4.y; v = v >= 0.f ? v : 0.2f * v; ss = fmaf(v, at4.y, ss);
      v = a[k].z + xr4.z; v = v >= 0.f ? v : 0.2f * v; ss = fmaf(v, at4.z, ss);
      v = a[k].w + xr4.w; v = v >= 0.f ? v : 0.2f * v; ss = fmaf(v, at4.w, ss);
      s[k] = ss;
    }
    #pragma unroll
    for (int k = 0; k < 8; ++k) {
      s[k] += __shfl_xor(s[k], 1);
      s[k] += __shfl_xor(s[k], 2);
      s[k] += __shfl_xor(s[k], 4);
    }
    float w[8];
    #pragma unroll
    for (int k = 0; k < 8; ++k)
      w[k] = (j0 + k <= jm) ? __expf(s[k] - SCORE_SHIFT) : 0.f;
    #pragma unroll
    for (int k = 0; k < 8; ++k) {
      acc.x = fmaf(w[k], a[k].x, acc.x);
      acc.y = fmaf(w[k], a[k].y, acc.y);
      acc.z = fmaf(w[k], a[k].z, acc.z);
      acc.w = fmaf(w[k], a[k].w, acc.w);
      den += w[k];
    }
  }
  const float inv_d = 1.f / den;
  const float4 bb = *(const float4*)(bias + lane * 4);
  float t0 = fmaf(acc.x, inv_d, bb.x); t0 = t0 > 0.f ? t0 : 0.f;
  float t1 = fmaf(acc.y, inv_d, bb.y); t1 = t1 > 0.f ? t1 : 0.f;
  float t2 = fmaf(acc.z, inv_d, bb.z); t2 = t2 > 0.f ? t2 : 0.f;
  float t3 = fmaf(acc.w, inv_d, bb.w); t3 = t3 > 0.f ? t3 : 0.f;

  if (MODE == 0) {
    float s = t0 + t1 + t2 + t3;
    #pragma unroll
    for (int mm = 1; mm < 64; mm <<= 1) s += __shfl_xor(s, mm);
    const float mu = s * (1.f / HIDDIM);
    const float d0 = t0 - mu, d1 = t1 - mu, d2 = t2 - mu, d3 = t3 - mu;
    float q = d0 * d0 + d1 * d1 + d2 * d2 + d3 * d3;
    #pragma unroll
    for (int mm = 1; mm < 64; mm <<= 1) q += __shfl_xor(q, mm);
    const float inv = rsqrtf(q * (1.f / HIDDIM) + 1e-5f);
    const float4 g4 = *(const float4*)(lng + lane * 4);
    const float4 b4 = *(const float4*)(lnb + lane * 4);
    half4s ho;
    ho.a = __floats2half2_rn(d0 * inv * g4.x + b4.x, d1 * inv * g4.y + b4.y);
    ho.b = __floats2half2_rn(d2 * inv * g4.z + b4.z, d3 * inv * g4.w + b4.w);
    *((half4s*)outp + (size_t)n * (HIDDIM / 4) + lane) = ho;
  } else {
    half4s ho;
    ho.a = __floats2half2_rn(t0, t1);
    ho.b = __floats2half2_rn(t2, t3);
    *((half4s*)outp + (size_t)n * (HIDDIM / 4) + lane) = ho;
  }
}

// ---------------- pool: per-graph contiguous streaming reduction ----------------
__global__ __launch_bounds__(256) void pool_kernel(
    const __half* __restrict__ tbuf, const int* __restrict__ gstart,
    float* __restrict__ pooled) {
  const int g = blockIdx.x, rc = blockIdx.y, ch = threadIdx.x;
  const int n0 = gstart[g], n1 = gstart[g + 1];
  float acc = 0.f;
  for (int n = n0 + rc; n < n1; n += 8)
    acc += __half2float(tbuf[(size_t)n * HIDDIM + ch]);
  atomicAdd(&pooled[g * HIDDIM + ch], acc);
}

// ---------------- head MLP: one block per graph ----------------
__global__ __launch_bounds__(256) void head_kernel(
    const float* __restrict__ pooled, const int* __restrict__ gstart,
    const float* __restrict__ h1w, const float* __restrict__ h1b,
    const float* __restrict__ h2w, const float* __restrict__ h2b,
    float* __restrict__ out, int H1, int OUT) {
  const int g = blockIdx.x;
  __shared__ float P[HIDDIM];
  __shared__ float Hh[128];
  const int tid = threadIdx.x;
  float cnt = (float)(gstart[g + 1] - gstart[g]);
  if (cnt < 1.f) cnt = 1.f;
  P[tid] = pooled[g * HIDDIM + tid] / cnt;
  __syncthreads();
  if (tid < H1) {
    float s = h1b[tid];
    for (int k = 0; k < HIDDIM; ++k) s = fmaf(P[k], h1w[k * H1 + tid], s);
    Hh[tid] = s > 0.f ? s : 0.f;
  }
  __syncthreads();
  if (tid < OUT) {
    float s = h2b[tid];
    for (int k = 0; k < H1; ++k) s = fmaf(Hh[k], h2w[k * OUT + tid], s);
    out[g * OUT + tid] = s;
  }
}

extern "C" void kernel_launch(void* const* d_in, const int* in_sizes, int n_in,
                              void* d_out, int out_size, void* d_ws, size_t ws_size,
                              hipStream_t stream) {
  const float* x = (const float*)d_in[0];
  const int* ei = (const int*)d_in[1];
  const int* batch = (const int*)d_in[2];
  const float* enc_w = (const float*)d_in[3];
  const float* enc_b = (const float*)d_in[4];
  const float* g_wl[2] = {(const float*)d_in[5], (const float*)d_in[11]};
  const float* g_bl[2] = {(const float*)d_in[6], (const float*)d_in[12]};
  const float* g_wr[2] = {(const float*)d_in[7], (const float*)d_in[13]};
  const float* g_br[2] = {(const float*)d_in[8], (const float*)d_in[14]};
  const float* g_att[2] = {(const float*)d_in[9], (const float*)d_in[15]};
  const float* g_bias[2] = {(const float*)d_in[10], (const float*)d_in[16]};
  const float* ln_g = (const float*)d_in[17];
  const float* ln_b = (const float*)d_in[18];
  const float* h1_w = (const float*)d_in[19];
  const float* h1_b = (const float*)d_in[20];
  const float* h2_w = (const float*)d_in[21];
  const float* h2_b = (const float*)d_in[22];
  float* out = (float*)d_out;

  const int N = in_sizes[2];          // 20000
  const int E = in_sizes[1] / 2;      // 320000
  const int DIN = in_sizes[0] / N;    // 128
  const int ET = E + N;
  const int H1 = in_sizes[20];        // 128
  const int OUT = in_sizes[22];       // 2
  const int G = out_size / OUT;       // 16

  char* base = (char*)d_ws;
  const size_t NH = (size_t)N * HIDDIM;
  __half* h16  = (__half*)base;                    // [N][256]
  __half* xlr  = h16 + NH;                         // [N][512]  (xl | xr)
  __half* tbuf = xlr + NH * 2;                     // [N][256]
  __half* x16  = tbuf + NH;                        // [N][DIN]
  __half* wtE  = x16 + (size_t)N * DIN;            // [256][DIN]
  __half* wtC0 = wtE + (size_t)HIDDIM * DIN;       // [512][256]
  __half* wtC1 = wtC0 + (size_t)XSTR * HIDDIM;     // [512][256]
  float* biasC0 = (float*)(wtC1 + (size_t)XSTR * HIDDIM);
  float* biasC1 = biasC0 + XSTR;
  float* pooled = biasC1 + XSTR;                   // [G][256]
  int* gstart = (int*)(pooled + (size_t)G * HIDDIM);  // [G+1]
  int* deg    = gstart + (G + 1);                  // [N]   (deg, cursor adjacent)
  int* cursor = deg + N;                           // [N]
  int* rowptr = cursor + N;                        // [N+1]
  int* csr    = rowptr + (N + 1);                  // [ET]

  const dim3 blk(256);
  const int eb = (ET + 255) / 256;
  const int nb = (N + 3) / 4;
  const dim3 enc_grid(HIDDIM / 128, (N + 127) / 128);
  const dim3 cmb_grid(XSTR / 128, (N + 127) / 128);

  // CSR build + graph ranges (graph identical for both layers)
  hipMemsetAsync(deg, 0, (size_t)2 * N * sizeof(int), stream);   // deg + cursor
  hipMemsetAsync(pooled, 0, (size_t)G * HIDDIM * sizeof(float), stream);
  count_deg<<<eb, blk, 0, stream>>>(ei, deg, E, N);
  scan_deg<<<1, 1024, 0, stream>>>(deg, rowptr, N);
  fill_csr<<<eb, blk, 0, stream>>>(ei, rowptr, cursor, csr, E, N);
  graph_ranges<<<(N + 256) / 256, blk, 0, stream>>>(batch, gstart, N, G);

  // weight/input conversion (merged launches)
  cvt_f2h<<<(N * DIN + 255) / 256, blk, 0, stream>>>(x, x16, N * DIN);
  cvt_transpose<<<(DIN * HIDDIM + 255) / 256, blk, 0, stream>>>(enc_w, wtE, DIN, HIDDIM);
  cvt_transpose4<<<dim3((HIDDIM * HIDDIM + 255) / 256, 4), blk, 0, stream>>>(
      g_wl[0], g_wr[0], g_wl[1], g_wr[1],
      wtC0, wtC0 + (size_t)HIDDIM * HIDDIM, wtC1, wtC1 + (size_t)HIDDIM * HIDDIM);
  concat_biases<<<(2 * XSTR + 255) / 256, blk, 0, stream>>>(
      g_bl[0], g_br[0], g_bl[1], g_br[1], biasC0, biasC1);

  // encoder: h16 = relu(x @ enc_w + enc_b)   (KT = 128)
  gemm_mfma<1, 128><<<enc_grid, blk, 0, stream>>>(
      (const _Float16*)x16, (const _Float16*)wtE, enc_b, (_Float16*)h16, N, HIDDIM);

  for (int L = 0; L < 2; ++L) {
    const __half* wtC = (L == 0) ? wtC0 : wtC1;
    const float* bC = (L == 0) ? biasC0 : biasC1;
    gemm_mfma<0, 256><<<cmb_grid, blk, 0, stream>>>(
        (const _Float16*)h16, (const _Float16*)wtC, bC, (_Float16*)xlr, N, XSTR);
    if (L == 0) {
      node_gat<0><<<nb, blk, 0, stream>>>(xlr, rowptr, csr, g_att[0], g_bias[0],
                                          ln_g, ln_b, h16, N);
    } else {
      node_gat<1><<<nb, blk, 0, stream>>>(xlr, rowptr, csr, g_att[1], g_bias[1],
                                          nullptr, nullptr, tbuf, N);
      pool_kernel<<<dim3(G, 8), blk, 0, stream>>>(tbuf, gstart, pooled);
    }
  }
  head_kernel<<<G, blk, 0, stream>>>(pooled, gstart, h1_w, h1_b, h2_w, h2_b, out, H1, OUT);
}